// Round 1
// baseline (275.506 us; speedup 1.0000x reference)
//
#include <hip/hip_runtime.h>

// NonLocalLayer  B=8, C=128, MID=64, OUT=128, T=4, N=512, TN=2048
// R19: attn restructured — swapped QK (mfma(phi,theta) -> C'[k,q]) plus a
// contraction-slot relabel so the PV A-frag is built from the lane's own
// QK output registers (zero shuffles, no P LDS round-trip). LDS 45.5K->18.5K,
// 3->2 barriers/kt. Workspace-tiered qsplit/ksplit up to 8 for occupancy.

constexpr int NL75_TN  = 2048;
constexpr int NL75_MID = 64;
constexpr int NL75_C   = 128;

typedef __attribute__((ext_vector_type(8))) short nl75_bf8;
typedef __attribute__((ext_vector_type(4))) float nl75_f4;

__device__ __forceinline__ unsigned short nl75_f2b(float f) {
  unsigned x = __float_as_uint(f);
  return (unsigned short)((x + 0x7fffu + ((x >> 16) & 1u)) >> 16);
}

__device__ __forceinline__ unsigned int nl75_pkbf16(float lo, float hi) {
  unsigned int r;
  asm("v_cvt_pk_bf16_f32 %0, %1, %2" : "=v"(r) : "v"(lo), "v"(hi));
  return r;
}

__global__ void NonLocalLayer_75771813036638_kernel() {}

// ---------------- projections: proj[pj][bl][m][q] (unchanged) ---------------
__global__ void nl75_proj(const float* pc, const float* w0, const float* b0,
                          const float* w1, const float* b1, const float* w2,
                          const float* b2, float* projB, int bOff, int nb) {
  __shared__ float wT[NL75_C][68];
  const int qt = blockIdx.x, pj = blockIdx.y, bl = blockIdx.z;
  const int b = bOff + bl;
  const float* wp = (pj == 0) ? w0 : (pj == 1) ? w1 : w2;
  const float* bp = (pj == 0) ? b0 : (pj == 1) ? b1 : b2;
  const int tid = threadIdx.x;
  for (int i = tid; i < NL75_MID * NL75_C; i += 256)
    wT[i & 127][i >> 7] = wp[i];
  __syncthreads();
  const int lq = tid & 63, mg = tid >> 6;
  const int q = qt * 64 + lq, m0 = mg * 16;
  const float* pcb = pc + (long long)b * NL75_C * NL75_TN + q;
  float acc[16];
#pragma unroll
  for (int i = 0; i < 16; i++) acc[i] = bp[m0 + i];
  for (int c = 0; c < NL75_C; c++) {
    float p = pcb[(long long)c * NL75_TN];
#pragma unroll
    for (int i = 0; i < 16; i++) acc[i] = fmaf(wT[c][m0 + i], p, acc[i]);
  }
  float* op = projB + ((long long)(pj * nb + bl) * NL75_MID) * NL75_TN + q;
#pragma unroll
  for (int i = 0; i < 16; i++)
    op[(long long)(m0 + i) * NL75_TN] = fmaxf(acc[i], 0.0f);
}

// ---- helper: stage transposed bf16 tile dst[x][m] from src[m][x0+x] --------
// dst pitch 72 shorts. 256 threads, 64x64 tile. 16 loads + 4 b64 writes/thr.
__device__ __forceinline__ void nl75_stageT(unsigned short* dst,
                                            const float* src, int x0,
                                            int tid) {
  const int x = tid & 63;
  const int mb = (tid >> 6) * 4;
#pragma unroll
  for (int mi = 0; mi < 4; mi++) {
    const int m4 = mb + mi * 16;
    ushort4 v;
    v.x = nl75_f2b(src[(long long)(m4 + 0) * NL75_TN + x0 + x]);
    v.y = nl75_f2b(src[(long long)(m4 + 1) * NL75_TN + x0 + x]);
    v.z = nl75_f2b(src[(long long)(m4 + 2) * NL75_TN + x0 + x]);
    v.w = nl75_f2b(src[(long long)(m4 + 3) * NL75_TN + x0 + x]);
    *(ushort4*)&dst[x * 72 + m4] = v;
  }
}

// ------------- partial softmax stats over a q-range (MFMA QK) ---------------
// grid (32*qsplit, nb), block 256.
__global__ void nl75_stats(const float* projB, float* Mp, float* Sp, int nb,
                           int qsplit) {
  __shared__ unsigned short phT[64 * 72];  // [k][m] bf16
  __shared__ unsigned short thT[64 * 72];  // [q][m] bf16
  const int kt = blockIdx.x & 31, qs = blockIdx.x >> 5, bl = blockIdx.y;
  const int tid = threadIdx.x;
  const float* thB = projB + ((long long)(0 * nb + bl) * NL75_MID) * NL75_TN;
  const float* phB = projB + ((long long)(1 * nb + bl) * NL75_MID) * NL75_TN;
  const int k0 = kt * 64;
  nl75_stageT(phT, phB, k0, tid);
  __syncthreads();
  const int lane = tid & 63, w = tid >> 6;
  const int l15 = lane & 15, quad = lane >> 4;
  // B-frags for this wave's 16 k columns (held in regs across all q)
  const nl75_bf8 b0 = *(const nl75_bf8*)&phT[(w * 16 + l15) * 72 + quad * 8];
  const nl75_bf8 b1 =
      *(const nl75_bf8*)&phT[(w * 16 + l15) * 72 + 32 + quad * 8];
  float M = -1e30f, S = 0.0f;
  const int qtN = 32 / qsplit;
  const int qtBeg = qs * qtN, qtEnd = qtBeg + qtN;
  for (int qt = qtBeg; qt < qtEnd; qt++) {
    __syncthreads();
    nl75_stageT(thT, thB, qt * 64, tid);
    __syncthreads();
#pragma unroll
    for (int q16 = 0; q16 < 4; q16++) {
      const nl75_bf8 a0 =
          *(const nl75_bf8*)&thT[(q16 * 16 + l15) * 72 + quad * 8];
      const nl75_bf8 a1 =
          *(const nl75_bf8*)&thT[(q16 * 16 + l15) * 72 + 32 + quad * 8];
      nl75_f4 c = {0.0f, 0.0f, 0.0f, 0.0f};
      c = __builtin_amdgcn_mfma_f32_16x16x32_bf16(a0, b0, c, 0, 0, 0);
      c = __builtin_amdgcn_mfma_f32_16x16x32_bf16(a1, b1, c, 0, 0, 0);
      float mx = fmaxf(fmaxf(c[0], c[1]), fmaxf(c[2], c[3]));
      float nM = fmaxf(M, mx);
      float sum = __expf(c[0] - nM) + __expf(c[1] - nM) + __expf(c[2] - nM) +
                  __expf(c[3] - nM);
      S = S * __expf(M - nM) + sum;
      M = nM;
    }
  }
  // combine the 4 quads (lanes k, k+16, k+32, k+48 share a column)
#pragma unroll
  for (int off = 16; off <= 32; off <<= 1) {
    float Mo = __shfl_xor(M, off);
    float So = __shfl_xor(S, off);
    float nM = fmaxf(M, Mo);
    S = S * __expf(M - nM) + So * __expf(Mo - nM);
    M = nM;
  }
  if (quad == 0) {
    const long long base = ((long long)(qs * nb + bl)) * NL75_TN + k0;
    Mp[base + w * 16 + l15] = M;
    Sp[base + w * 16 + l15] = S;
  }
}

// ------------- combine partial stats (unchanged) ----------------------------
__global__ void nl75_sred(const float* Mp, const float* Sp, float* mW,
                          float* izW, int nb, int qsplit) {
  const int bl = blockIdx.x;
  for (int k = threadIdx.x; k < NL75_TN; k += 256) {
    float M = -1e30f;
    for (int qs = 0; qs < qsplit; qs++)
      M = fmaxf(M, Mp[((long long)(qs * nb + bl)) * NL75_TN + k]);
    float S = 0.0f;
    for (int qs = 0; qs < qsplit; qs++) {
      long long idx = ((long long)(qs * nb + bl)) * NL75_TN + k;
      S += Sp[idx] * __expf(Mp[idx] - M);
    }
    mW[(long long)bl * NL75_TN + k] = M;
    izW[(long long)bl * NL75_TN + k] = 1.0f / S;
  }
}

// ------------- attention apply + PV over a k-range (swapped-QK MFMA) --------
// grid (32, ksplit, nb), block 256. LDS 18944 B.
// QK computed as C'[k,q] = mfma(phi, theta); with the contraction-slot
// relabel k(slot=8*quad+j) = 16*(j>>2) + 4*quad + (j&3), the PV A-frag is
// the lane's own exp-scaled C' registers (cvt_pk packed) -- no LDS P tile.
__global__ void nl75_attn(const float* projB, const float* mIn,
                          const float* izIn, float* yPart, int nb,
                          int ksplit) {
  __shared__ __align__(16) char smem[18944];
  unsigned short* AT = (unsigned short*)smem;           // [x][m], pitch 72
  unsigned short* gS = (unsigned short*)(smem + 9216);  // [m][k], pitch 72
  float* mT = (float*)(smem + 18432);
  float* izT = (float*)(smem + 18688);
  const int qt = blockIdx.x, ks = blockIdx.y, bl = blockIdx.z;
  const int tid = threadIdx.x;
  const float* thB = projB + ((long long)(0 * nb + bl) * NL75_MID) * NL75_TN;
  const float* phB = projB + ((long long)(1 * nb + bl) * NL75_MID) * NL75_TN;
  const float* gB  = projB + ((long long)(2 * nb + bl) * NL75_MID) * NL75_TN;
  const int q0 = qt * 64;
  // stage theta once, pull frags to registers, then AT is reused for phi
  nl75_stageT(AT, thB, q0, tid);
  __syncthreads();
  const int lane = tid & 63, w = tid >> 6;
  const int l15 = lane & 15, quad = lane >> 4;
  const nl75_bf8 aq0 = *(const nl75_bf8*)&AT[(w * 16 + l15) * 72 + quad * 8];
  const nl75_bf8 aq1 =
      *(const nl75_bf8*)&AT[(w * 16 + l15) * 72 + 32 + quad * 8];
  nl75_f4 yacc[4];
#pragma unroll
  for (int i = 0; i < 4; i++) yacc[i] = (nl75_f4){0.0f, 0.0f, 0.0f, 0.0f};
  const int ktN = 32 / ksplit;
  const int ktBeg = ks * ktN, ktEnd = ktBeg + ktN;
  for (int kt = ktBeg; kt < ktEnd; kt++) {
    const int k0 = kt * 64;
    __syncthreads();  // theta frag loads done / prior QK+PV LDS reads done
    nl75_stageT(AT, phB, k0, tid);  // phi [k][m]
    // g: [m][k] natural layout, ushort2 packed writes
    for (int idx = tid; idx < 64 * 32; idx += 256) {
      const int m = idx >> 5, k2 = (idx & 31) * 2;
      const float* gp = &gB[(long long)m * NL75_TN + k0 + k2];
      ushort2 v;
      v.x = nl75_f2b(gp[0]);
      v.y = nl75_f2b(gp[1]);
      *(ushort2*)&gS[m * 72 + k2] = v;
    }
    if (tid < 64) {
      mT[tid] = mIn[(long long)bl * NL75_TN + k0 + tid];
      izT[tid] = izIn[(long long)bl * NL75_TN + k0 + tid];
    }
    __syncthreads();
    // QK swapped: per ktile this lane gets C'[k=kt16+4*quad+reg][q=w16+l15];
    // exp-scale and pack to bf16 pairs entirely in registers.
    unsigned int pk[8];
#pragma unroll
    for (int t = 0; t < 4; t++) {
      const nl75_bf8 b0 = *(const nl75_bf8*)&AT[(t * 16 + l15) * 72 + quad * 8];
      const nl75_bf8 b1 =
          *(const nl75_bf8*)&AT[(t * 16 + l15) * 72 + 32 + quad * 8];
      nl75_f4 c = {0.0f, 0.0f, 0.0f, 0.0f};
      c = __builtin_amdgcn_mfma_f32_16x16x32_bf16(b0, aq0, c, 0, 0, 0);
      c = __builtin_amdgcn_mfma_f32_16x16x32_bf16(b1, aq1, c, 0, 0, 0);
      const nl75_f4 mk = *(const nl75_f4*)&mT[t * 16 + quad * 4];
      const nl75_f4 zk = *(const nl75_f4*)&izT[t * 16 + quad * 4];
      const float p0 = __expf(c[0] - mk[0]) * zk[0];
      const float p1 = __expf(c[1] - mk[1]) * zk[1];
      const float p2 = __expf(c[2] - mk[2]) * zk[2];
      const float p3 = __expf(c[3] - mk[3]) * zk[3];
      pk[t * 2 + 0] = nl75_pkbf16(p0, p1);
      pk[t * 2 + 1] = nl75_pkbf16(p2, p3);
    }
    // PV: A-frag = own pk registers; B-frag = g rows read with the matching
    // slot relabel: slot 8q+j -> k = 16*(j>>2) + 4*q + (j&3).
    union Frag { nl75_bf8 h; unsigned int u[4]; };
    Frag ap0, ap1;
    ap0.u[0] = pk[0]; ap0.u[1] = pk[1]; ap0.u[2] = pk[2]; ap0.u[3] = pk[3];
    ap1.u[0] = pk[4]; ap1.u[1] = pk[5]; ap1.u[2] = pk[6]; ap1.u[3] = pk[7];
#pragma unroll
    for (int mtile = 0; mtile < 4; mtile++) {
      const unsigned short* row = &gS[(mtile * 16 + l15) * 72];
      Frag bg0, bg1;
      *(uint2*)&bg0.u[0] = *(const uint2*)&row[quad * 4];
      *(uint2*)&bg0.u[2] = *(const uint2*)&row[16 + quad * 4];
      *(uint2*)&bg1.u[0] = *(const uint2*)&row[32 + quad * 4];
      *(uint2*)&bg1.u[2] = *(const uint2*)&row[48 + quad * 4];
      yacc[mtile] =
          __builtin_amdgcn_mfma_f32_16x16x32_bf16(ap0.h, bg0.h, yacc[mtile], 0, 0, 0);
      yacc[mtile] =
          __builtin_amdgcn_mfma_f32_16x16x32_bf16(ap1.h, bg1.h, yacc[mtile], 0, 0, 0);
    }
  }
  __syncthreads();
  // write y via LDS transpose (reuse smem as fp32 y[m][q]) then coalesced out
  float* ybuf = (float*)smem;
#pragma unroll
  for (int mtile = 0; mtile < 4; mtile++)
#pragma unroll
    for (int r = 0; r < 4; r++)
      ybuf[(mtile * 16 + l15) * 68 + (w * 16 + quad * 4 + r)] = yacc[mtile][r];
  __syncthreads();
  float* yB = yPart + ((long long)(ks * nb + bl) * NL75_MID) * NL75_TN;
  const int qw = tid & 63;
#pragma unroll
  for (int mi = 0; mi < 16; mi++) {
    const int m = (tid >> 6) + mi * 4;
    yB[(long long)m * NL75_TN + q0 + qw] = ybuf[m * 68 + qw];
  }
}

// ------- fused refine GEMM + scatter + residual (unchanged) -----------------
__global__ void nl75_refsc(const float* yPart, const float* rW,
                           const float* rB, const float* pc, float* outP,
                           int bOff, int nb, int ksplit) {
  __shared__ float rwS[32][66];
  __shared__ float yS[NL75_MID][132];
  const int cg = blockIdx.x, t = blockIdx.y, bl = blockIdx.z;
  const int b = bOff + bl, c0 = cg * 8, tid = threadIdx.x;
  for (int i = tid; i < 32 * NL75_MID; i += 256) {
    int oh = i >> 6, m = i & 63;
    rwS[oh][m] = rW[(long long)(t * 32 + oh) * NL75_MID + m];
  }
  for (int i = tid; i < NL75_MID * 128; i += 256) {
    int m = i >> 7, qi = i & 127;
    int i16 = qi >> 3, cl = qi & 7;
    long long off = (long long)m * NL75_TN + i16 * 128 + c0 + cl;
    float v = 0.0f;
    for (int ks = 0; ks < ksplit; ks++)
      v += yPart[((long long)(ks * nb + bl) * NL75_MID) * NL75_TN + off];
    yS[m][qi] = v;
  }
  __syncthreads();
  const int oh0 = (tid >> 5) * 4;
  const int q4 = (tid & 31) * 4;
  float acc[4][4];
#pragma unroll
  for (int i = 0; i < 4; i++) {
    float bias = rB[t * 32 + oh0 + i];
#pragma unroll
    for (int j = 0; j < 4; j++) acc[i][j] = bias;
  }
  for (int m = 0; m < NL75_MID; m++) {
    float yv[4];
#pragma unroll
    for (int j = 0; j < 4; j++) yv[j] = yS[m][q4 + j];
#pragma unroll
    for (int i = 0; i < 4; i++) {
      float w = rwS[oh0 + i][m];
#pragma unroll
      for (int j = 0; j < 4; j++) acc[i][j] = fmaf(w, yv[j], acc[i][j]);
    }
  }
#pragma unroll
  for (int i = 0; i < 4; i++) {
    int oh = oh0 + i;
#pragma unroll
    for (int j = 0; j < 4; j++) {
      int qi = q4 + j;
      int i16 = qi >> 3, cl = qi & 7;
      int n = oh * 16 + i16;
      long long idx = (((long long)b * 128 + c0 + cl) * 4 + t) * 512 + n;
      outP[idx] = fmaxf(acc[i][j], 0.0f) + pc[idx];
    }
  }
}

extern "C" void kernel_launch(void* const* d_in, const int* in_sizes, int n_in,
                              void* d_out, int out_size, void* d_ws, size_t ws_size,
                              hipStream_t stream) {
  const float* pc = (const float*)d_in[0];
  const float* tw = (const float*)d_in[1];
  const float* tb = (const float*)d_in[2];
  const float* pw = (const float*)d_in[3];
  const float* pb = (const float*)d_in[4];
  const float* gw = (const float*)d_in[5];
  const float* gb = (const float*)d_in[6];
  const float* rw = (const float*)d_in[7];
  const float* rb = (const float*)d_in[8];
  float* out = (float*)d_out;

  const size_t projPB = 3ull * NL75_MID * NL75_TN;
  const size_t yPB = (size_t)NL75_MID * NL75_TN;
  // need(qs,ks) in bytes for nb=8, non-aliased
  auto need = [&](int qs, int ks) -> size_t {
    return (projPB * 8 + 2ull * 8 * NL75_TN + 2ull * (size_t)qs * 8 * NL75_TN +
            (size_t)ks * 8 * yPB) * 4;
  };
  const size_t needMid = (projPB * 8 + 2ull * 8 * NL75_TN + 8ull * yPB) * 4;

  int nb, qsplit, ksplit;
  bool alias;
  if (ws_size >= need(8, 8))      { nb = 8; qsplit = 8; ksplit = 8; alias = false; }
  else if (ws_size >= need(8, 4)) { nb = 8; qsplit = 8; ksplit = 4; alias = false; }
  else if (ws_size >= need(4, 4)) { nb = 8; qsplit = 4; ksplit = 4; alias = false; }
  else if (ws_size >= needMid)    { nb = 8; qsplit = 1; ksplit = 1; alias = true; }
  else                            { nb = 1; qsplit = 1; ksplit = 1; alias = true; }
  const int nloop = 8 / nb;

  float* projB = (float*)d_ws;
  float* mW = projB + projPB * nb;
  float* izW = mW + (size_t)nb * NL75_TN;
  float* Mp, * Sp, * yPart;
  if (alias) {
    Mp = mW; Sp = izW;
    yPart = izW + (size_t)nb * NL75_TN;
  } else {
    Mp = izW + (size_t)nb * NL75_TN;
    Sp = Mp + (size_t)qsplit * nb * NL75_TN;
    yPart = Sp + (size_t)qsplit * nb * NL75_TN;
  }

  for (int l = 0; l < nloop; l++) {
    const int bOff = l * nb;
    nl75_proj<<<dim3(32, 3, nb), 256, 0, stream>>>(pc, tw, tb, pw, pb, gw, gb,
                                                   projB, bOff, nb);
    nl75_stats<<<dim3(32 * qsplit, nb), 256, 0, stream>>>(projB, Mp, Sp, nb,
                                                          qsplit);
    nl75_sred<<<dim3(nb), 256, 0, stream>>>(Mp, Sp, mW, izW, nb, qsplit);
    nl75_attn<<<dim3(32, ksplit, nb), 256, 0, stream>>>(projB, mW, izW, yPart,
                                                        nb, ksplit);
    nl75_refsc<<<dim3(16, 4, nb), 256, 0, stream>>>(yPart, rw, rb, pc, out,
                                                    bOff, nb, ksplit);
  }
}

// Round 2
// 216.400 us; speedup vs baseline: 1.2731x; 1.2731x over previous
//
#include <hip/hip_runtime.h>

// NonLocalLayer  B=8, C=128, MID=64, OUT=128, T=4, N=512, TN=2048
// R20: R19 attn (swapped-QK, zero-shuffle PV) + new nl75_yred streaming
// reduction so refsc reads the 4 MB reduced y once instead of gathering
// ksplit x t-redundant yPart partials (refsc FETCH 68 MB -> ~15 MB).

constexpr int NL75_TN  = 2048;
constexpr int NL75_MID = 64;
constexpr int NL75_C   = 128;

typedef __attribute__((ext_vector_type(8))) short nl75_bf8;
typedef __attribute__((ext_vector_type(4))) float nl75_f4;

__device__ __forceinline__ unsigned short nl75_f2b(float f) {
  unsigned x = __float_as_uint(f);
  return (unsigned short)((x + 0x7fffu + ((x >> 16) & 1u)) >> 16);
}

__device__ __forceinline__ unsigned int nl75_pkbf16(float lo, float hi) {
  unsigned int r;
  asm("v_cvt_pk_bf16_f32 %0, %1, %2" : "=v"(r) : "v"(lo), "v"(hi));
  return r;
}

__global__ void NonLocalLayer_75771813036638_kernel() {}

// ---------------- projections: proj[pj][bl][m][q] (unchanged) ---------------
__global__ void nl75_proj(const float* pc, const float* w0, const float* b0,
                          const float* w1, const float* b1, const float* w2,
                          const float* b2, float* projB, int bOff, int nb) {
  __shared__ float wT[NL75_C][68];
  const int qt = blockIdx.x, pj = blockIdx.y, bl = blockIdx.z;
  const int b = bOff + bl;
  const float* wp = (pj == 0) ? w0 : (pj == 1) ? w1 : w2;
  const float* bp = (pj == 0) ? b0 : (pj == 1) ? b1 : b2;
  const int tid = threadIdx.x;
  for (int i = tid; i < NL75_MID * NL75_C; i += 256)
    wT[i & 127][i >> 7] = wp[i];
  __syncthreads();
  const int lq = tid & 63, mg = tid >> 6;
  const int q = qt * 64 + lq, m0 = mg * 16;
  const float* pcb = pc + (long long)b * NL75_C * NL75_TN + q;
  float acc[16];
#pragma unroll
  for (int i = 0; i < 16; i++) acc[i] = bp[m0 + i];
  for (int c = 0; c < NL75_C; c++) {
    float p = pcb[(long long)c * NL75_TN];
#pragma unroll
    for (int i = 0; i < 16; i++) acc[i] = fmaf(wT[c][m0 + i], p, acc[i]);
  }
  float* op = projB + ((long long)(pj * nb + bl) * NL75_MID) * NL75_TN + q;
#pragma unroll
  for (int i = 0; i < 16; i++)
    op[(long long)(m0 + i) * NL75_TN] = fmaxf(acc[i], 0.0f);
}

// ---- helper: stage transposed bf16 tile dst[x][m] from src[m][x0+x] --------
__device__ __forceinline__ void nl75_stageT(unsigned short* dst,
                                            const float* src, int x0,
                                            int tid) {
  const int x = tid & 63;
  const int mb = (tid >> 6) * 4;
#pragma unroll
  for (int mi = 0; mi < 4; mi++) {
    const int m4 = mb + mi * 16;
    ushort4 v;
    v.x = nl75_f2b(src[(long long)(m4 + 0) * NL75_TN + x0 + x]);
    v.y = nl75_f2b(src[(long long)(m4 + 1) * NL75_TN + x0 + x]);
    v.z = nl75_f2b(src[(long long)(m4 + 2) * NL75_TN + x0 + x]);
    v.w = nl75_f2b(src[(long long)(m4 + 3) * NL75_TN + x0 + x]);
    *(ushort4*)&dst[x * 72 + m4] = v;
  }
}

// ------------- partial softmax stats over a q-range (MFMA QK) ---------------
__global__ void nl75_stats(const float* projB, float* Mp, float* Sp, int nb,
                           int qsplit) {
  __shared__ unsigned short phT[64 * 72];  // [k][m] bf16
  __shared__ unsigned short thT[64 * 72];  // [q][m] bf16
  const int kt = blockIdx.x & 31, qs = blockIdx.x >> 5, bl = blockIdx.y;
  const int tid = threadIdx.x;
  const float* thB = projB + ((long long)(0 * nb + bl) * NL75_MID) * NL75_TN;
  const float* phB = projB + ((long long)(1 * nb + bl) * NL75_MID) * NL75_TN;
  const int k0 = kt * 64;
  nl75_stageT(phT, phB, k0, tid);
  __syncthreads();
  const int lane = tid & 63, w = tid >> 6;
  const int l15 = lane & 15, quad = lane >> 4;
  const nl75_bf8 b0 = *(const nl75_bf8*)&phT[(w * 16 + l15) * 72 + quad * 8];
  const nl75_bf8 b1 =
      *(const nl75_bf8*)&phT[(w * 16 + l15) * 72 + 32 + quad * 8];
  float M = -1e30f, S = 0.0f;
  const int qtN = 32 / qsplit;
  const int qtBeg = qs * qtN, qtEnd = qtBeg + qtN;
  for (int qt = qtBeg; qt < qtEnd; qt++) {
    __syncthreads();
    nl75_stageT(thT, thB, qt * 64, tid);
    __syncthreads();
#pragma unroll
    for (int q16 = 0; q16 < 4; q16++) {
      const nl75_bf8 a0 =
          *(const nl75_bf8*)&thT[(q16 * 16 + l15) * 72 + quad * 8];
      const nl75_bf8 a1 =
          *(const nl75_bf8*)&thT[(q16 * 16 + l15) * 72 + 32 + quad * 8];
      nl75_f4 c = {0.0f, 0.0f, 0.0f, 0.0f};
      c = __builtin_amdgcn_mfma_f32_16x16x32_bf16(a0, b0, c, 0, 0, 0);
      c = __builtin_amdgcn_mfma_f32_16x16x32_bf16(a1, b1, c, 0, 0, 0);
      float mx = fmaxf(fmaxf(c[0], c[1]), fmaxf(c[2], c[3]));
      float nM = fmaxf(M, mx);
      float sum = __expf(c[0] - nM) + __expf(c[1] - nM) + __expf(c[2] - nM) +
                  __expf(c[3] - nM);
      S = S * __expf(M - nM) + sum;
      M = nM;
    }
  }
#pragma unroll
  for (int off = 16; off <= 32; off <<= 1) {
    float Mo = __shfl_xor(M, off);
    float So = __shfl_xor(S, off);
    float nM = fmaxf(M, Mo);
    S = S * __expf(M - nM) + So * __expf(Mo - nM);
    M = nM;
  }
  if (quad == 0) {
    const long long base = ((long long)(qs * nb + bl)) * NL75_TN + k0;
    Mp[base + w * 16 + l15] = M;
    Sp[base + w * 16 + l15] = S;
  }
}

// ------------- combine partial stats (unchanged) ----------------------------
__global__ void nl75_sred(const float* Mp, const float* Sp, float* mW,
                          float* izW, int nb, int qsplit) {
  const int bl = blockIdx.x;
  for (int k = threadIdx.x; k < NL75_TN; k += 256) {
    float M = -1e30f;
    for (int qs = 0; qs < qsplit; qs++)
      M = fmaxf(M, Mp[((long long)(qs * nb + bl)) * NL75_TN + k]);
    float S = 0.0f;
    for (int qs = 0; qs < qsplit; qs++) {
      long long idx = ((long long)(qs * nb + bl)) * NL75_TN + k;
      S += Sp[idx] * __expf(Mp[idx] - M);
    }
    mW[(long long)bl * NL75_TN + k] = M;
    izW[(long long)bl * NL75_TN + k] = 1.0f / S;
  }
}

// ------------- attention apply + PV over a k-range (swapped-QK MFMA) --------
// grid (32, ksplit, nb), block 256. LDS 18944 B. (unchanged from R19)
__global__ void nl75_attn(const float* projB, const float* mIn,
                          const float* izIn, float* yPart, int nb,
                          int ksplit) {
  __shared__ __align__(16) char smem[18944];
  unsigned short* AT = (unsigned short*)smem;           // [x][m], pitch 72
  unsigned short* gS = (unsigned short*)(smem + 9216);  // [m][k], pitch 72
  float* mT = (float*)(smem + 18432);
  float* izT = (float*)(smem + 18688);
  const int qt = blockIdx.x, ks = blockIdx.y, bl = blockIdx.z;
  const int tid = threadIdx.x;
  const float* thB = projB + ((long long)(0 * nb + bl) * NL75_MID) * NL75_TN;
  const float* phB = projB + ((long long)(1 * nb + bl) * NL75_MID) * NL75_TN;
  const float* gB  = projB + ((long long)(2 * nb + bl) * NL75_MID) * NL75_TN;
  const int q0 = qt * 64;
  nl75_stageT(AT, thB, q0, tid);
  __syncthreads();
  const int lane = tid & 63, w = tid >> 6;
  const int l15 = lane & 15, quad = lane >> 4;
  const nl75_bf8 aq0 = *(const nl75_bf8*)&AT[(w * 16 + l15) * 72 + quad * 8];
  const nl75_bf8 aq1 =
      *(const nl75_bf8*)&AT[(w * 16 + l15) * 72 + 32 + quad * 8];
  nl75_f4 yacc[4];
#pragma unroll
  for (int i = 0; i < 4; i++) yacc[i] = (nl75_f4){0.0f, 0.0f, 0.0f, 0.0f};
  const int ktN = 32 / ksplit;
  const int ktBeg = ks * ktN, ktEnd = ktBeg + ktN;
  for (int kt = ktBeg; kt < ktEnd; kt++) {
    const int k0 = kt * 64;
    __syncthreads();
    nl75_stageT(AT, phB, k0, tid);  // phi [k][m]
    for (int idx = tid; idx < 64 * 32; idx += 256) {
      const int m = idx >> 5, k2 = (idx & 31) * 2;
      const float* gp = &gB[(long long)m * NL75_TN + k0 + k2];
      ushort2 v;
      v.x = nl75_f2b(gp[0]);
      v.y = nl75_f2b(gp[1]);
      *(ushort2*)&gS[m * 72 + k2] = v;
    }
    if (tid < 64) {
      mT[tid] = mIn[(long long)bl * NL75_TN + k0 + tid];
      izT[tid] = izIn[(long long)bl * NL75_TN + k0 + tid];
    }
    __syncthreads();
    unsigned int pk[8];
#pragma unroll
    for (int t = 0; t < 4; t++) {
      const nl75_bf8 b0 = *(const nl75_bf8*)&AT[(t * 16 + l15) * 72 + quad * 8];
      const nl75_bf8 b1 =
          *(const nl75_bf8*)&AT[(t * 16 + l15) * 72 + 32 + quad * 8];
      nl75_f4 c = {0.0f, 0.0f, 0.0f, 0.0f};
      c = __builtin_amdgcn_mfma_f32_16x16x32_bf16(b0, aq0, c, 0, 0, 0);
      c = __builtin_amdgcn_mfma_f32_16x16x32_bf16(b1, aq1, c, 0, 0, 0);
      const nl75_f4 mk = *(const nl75_f4*)&mT[t * 16 + quad * 4];
      const nl75_f4 zk = *(const nl75_f4*)&izT[t * 16 + quad * 4];
      const float p0 = __expf(c[0] - mk[0]) * zk[0];
      const float p1 = __expf(c[1] - mk[1]) * zk[1];
      const float p2 = __expf(c[2] - mk[2]) * zk[2];
      const float p3 = __expf(c[3] - mk[3]) * zk[3];
      pk[t * 2 + 0] = nl75_pkbf16(p0, p1);
      pk[t * 2 + 1] = nl75_pkbf16(p2, p3);
    }
    union Frag { nl75_bf8 h; unsigned int u[4]; };
    Frag ap0, ap1;
    ap0.u[0] = pk[0]; ap0.u[1] = pk[1]; ap0.u[2] = pk[2]; ap0.u[3] = pk[3];
    ap1.u[0] = pk[4]; ap1.u[1] = pk[5]; ap1.u[2] = pk[6]; ap1.u[3] = pk[7];
#pragma unroll
    for (int mtile = 0; mtile < 4; mtile++) {
      const unsigned short* row = &gS[(mtile * 16 + l15) * 72];
      Frag bg0, bg1;
      *(uint2*)&bg0.u[0] = *(const uint2*)&row[quad * 4];
      *(uint2*)&bg0.u[2] = *(const uint2*)&row[16 + quad * 4];
      *(uint2*)&bg1.u[0] = *(const uint2*)&row[32 + quad * 4];
      *(uint2*)&bg1.u[2] = *(const uint2*)&row[48 + quad * 4];
      yacc[mtile] =
          __builtin_amdgcn_mfma_f32_16x16x32_bf16(ap0.h, bg0.h, yacc[mtile], 0, 0, 0);
      yacc[mtile] =
          __builtin_amdgcn_mfma_f32_16x16x32_bf16(ap1.h, bg1.h, yacc[mtile], 0, 0, 0);
    }
  }
  __syncthreads();
  float* ybuf = (float*)smem;
#pragma unroll
  for (int mtile = 0; mtile < 4; mtile++)
#pragma unroll
    for (int r = 0; r < 4; r++)
      ybuf[(mtile * 16 + l15) * 68 + (w * 16 + quad * 4 + r)] = yacc[mtile][r];
  __syncthreads();
  float* yB = yPart + ((long long)(ks * nb + bl) * NL75_MID) * NL75_TN;
  const int qw = tid & 63;
#pragma unroll
  for (int mi = 0; mi < 16; mi++) {
    const int m = (tid >> 6) + mi * 4;
    yB[(long long)m * NL75_TN + q0 + qw] = ybuf[m * 68 + qw];
  }
}

// ------- streaming ksplit-reduction: y = sum_ks yPart[ks] -------------------
// grid 1024, block 256, float4 fully coalesced. ~36 MB traffic.
__global__ void nl75_yred(const float* yPart, float* y, int nb, int ksplit) {
  const size_t tot = (size_t)nb * NL75_MID * NL75_TN / 4;
  const size_t stride = tot;  // ks stride in float4 units
  const float4* src = (const float4*)yPart;
  float4* dst = (float4*)y;
  for (size_t i = (size_t)blockIdx.x * 256 + threadIdx.x; i < tot;
       i += (size_t)gridDim.x * 256) {
    float4 a = src[i];
    for (int ks = 1; ks < ksplit; ks++) {
      float4 b = src[(size_t)ks * stride + i];
      a.x += b.x; a.y += b.y; a.z += b.z; a.w += b.w;
    }
    dst[i] = a;
  }
}

// ------- fused refine GEMM + scatter + residual -----------------------------
// With yred, called with (y, ksplit=1); fallback tiers pass yPart + ksplit.
__global__ void nl75_refsc(const float* yPart, const float* rW,
                           const float* rB, const float* pc, float* outP,
                           int bOff, int nb, int ksplit) {
  __shared__ float rwS[32][66];
  __shared__ float yS[NL75_MID][132];
  const int cg = blockIdx.x, t = blockIdx.y, bl = blockIdx.z;
  const int b = bOff + bl, c0 = cg * 8, tid = threadIdx.x;
  for (int i = tid; i < 32 * NL75_MID; i += 256) {
    int oh = i >> 6, m = i & 63;
    rwS[oh][m] = rW[(long long)(t * 32 + oh) * NL75_MID + m];
  }
  for (int i = tid; i < NL75_MID * 128; i += 256) {
    int m = i >> 7, qi = i & 127;
    int i16 = qi >> 3, cl = qi & 7;
    long long off = (long long)m * NL75_TN + i16 * 128 + c0 + cl;
    float v = 0.0f;
    for (int ks = 0; ks < ksplit; ks++)
      v += yPart[((long long)(ks * nb + bl) * NL75_MID) * NL75_TN + off];
    yS[m][qi] = v;
  }
  __syncthreads();
  const int oh0 = (tid >> 5) * 4;
  const int q4 = (tid & 31) * 4;
  float acc[4][4];
#pragma unroll
  for (int i = 0; i < 4; i++) {
    float bias = rB[t * 32 + oh0 + i];
#pragma unroll
    for (int j = 0; j < 4; j++) acc[i][j] = bias;
  }
  for (int m = 0; m < NL75_MID; m++) {
    float yv[4];
#pragma unroll
    for (int j = 0; j < 4; j++) yv[j] = yS[m][q4 + j];
#pragma unroll
    for (int i = 0; i < 4; i++) {
      float w = rwS[oh0 + i][m];
#pragma unroll
      for (int j = 0; j < 4; j++) acc[i][j] = fmaf(w, yv[j], acc[i][j]);
    }
  }
#pragma unroll
  for (int i = 0; i < 4; i++) {
    int oh = oh0 + i;
#pragma unroll
    for (int j = 0; j < 4; j++) {
      int qi = q4 + j;
      int i16 = qi >> 3, cl = qi & 7;
      int n = oh * 16 + i16;
      long long idx = (((long long)b * 128 + c0 + cl) * 4 + t) * 512 + n;
      outP[idx] = fmaxf(acc[i][j], 0.0f) + pc[idx];
    }
  }
}

extern "C" void kernel_launch(void* const* d_in, const int* in_sizes, int n_in,
                              void* d_out, int out_size, void* d_ws, size_t ws_size,
                              hipStream_t stream) {
  const float* pc = (const float*)d_in[0];
  const float* tw = (const float*)d_in[1];
  const float* tb = (const float*)d_in[2];
  const float* pw = (const float*)d_in[3];
  const float* pb = (const float*)d_in[4];
  const float* gw = (const float*)d_in[5];
  const float* gb = (const float*)d_in[6];
  const float* rw = (const float*)d_in[7];
  const float* rb = (const float*)d_in[8];
  float* out = (float*)d_out;

  const size_t projPB = 3ull * NL75_MID * NL75_TN;
  const size_t yPB = (size_t)NL75_MID * NL75_TN;
  // need(qs,ks,yred) in bytes for nb=8, non-aliased
  auto need = [&](int qs, int ks, int yr) -> size_t {
    return (projPB * 8 + 2ull * 8 * NL75_TN + 2ull * (size_t)qs * 8 * NL75_TN +
            (size_t)ks * 8 * yPB + (size_t)yr * 8 * yPB) * 4;
  };
  const size_t needMid = (projPB * 8 + 2ull * 8 * NL75_TN + 8ull * yPB) * 4;

  int nb, qsplit, ksplit;
  bool alias, yred;
  if (ws_size >= need(8, 8, 1)) {
    nb = 8; qsplit = 8; ksplit = 8; alias = false; yred = true;
  } else if (ws_size >= need(8, 4, 1)) {
    nb = 8; qsplit = 8; ksplit = 4; alias = false; yred = true;
  } else if (ws_size >= need(4, 4, 1)) {
    nb = 8; qsplit = 4; ksplit = 4; alias = false; yred = true;
  } else if (ws_size >= need(4, 4, 0)) {
    nb = 8; qsplit = 4; ksplit = 4; alias = false; yred = false;
  } else if (ws_size >= needMid) {
    nb = 8; qsplit = 1; ksplit = 1; alias = true; yred = false;
  } else {
    nb = 1; qsplit = 1; ksplit = 1; alias = true; yred = false;
  }
  const int nloop = 8 / nb;

  float* projB = (float*)d_ws;
  float* mW = projB + projPB * nb;
  float* izW = mW + (size_t)nb * NL75_TN;
  float* Mp, * Sp, * yPart, * yFull;
  if (alias) {
    Mp = mW; Sp = izW;
    yPart = izW + (size_t)nb * NL75_TN;
    yFull = yPart;
  } else {
    Mp = izW + (size_t)nb * NL75_TN;
    Sp = Mp + (size_t)qsplit * nb * NL75_TN;
    yPart = Sp + (size_t)qsplit * nb * NL75_TN;
    yFull = yPart + (size_t)ksplit * nb * yPB;
  }

  for (int l = 0; l < nloop; l++) {
    const int bOff = l * nb;
    nl75_proj<<<dim3(32, 3, nb), 256, 0, stream>>>(pc, tw, tb, pw, pb, gw, gb,
                                                   projB, bOff, nb);
    nl75_stats<<<dim3(32 * qsplit, nb), 256, 0, stream>>>(projB, Mp, Sp, nb,
                                                          qsplit);
    nl75_sred<<<dim3(nb), 256, 0, stream>>>(Mp, Sp, mW, izW, nb, qsplit);
    nl75_attn<<<dim3(32, ksplit, nb), 256, 0, stream>>>(projB, mW, izW, yPart,
                                                        nb, ksplit);
    if (yred) {
      nl75_yred<<<dim3(1024), 256, 0, stream>>>(yPart, yFull, nb, ksplit);
      nl75_refsc<<<dim3(16, 4, nb), 256, 0, stream>>>(yFull, rw, rb, pc, out,
                                                      bOff, nb, 1);
    } else {
      nl75_refsc<<<dim3(16, 4, nb), 256, 0, stream>>>(yPart, rw, rb, pc, out,
                                                      bOff, nb, ksplit);
    }
  }
}

// Round 3
// 213.141 us; speedup vs baseline: 1.2926x; 1.0153x over previous
//
#include <hip/hip_runtime.h>

// NonLocalLayer  B=8, C=128, MID=64, OUT=128, T=4, N=512, TN=2048
// R21: proj emits bf16 in frag-ready layouts (thT[q][m], phT[k][m], g[m][k]);
// stats and attn become LDS-free/barrier-free (frags loaded directly from
// L2-resident global), attn does 2 q-tiles/block with direct float4 y-store.
// Grids reordered so bl is fastest block index (XCD-pinned L2 reuse).

constexpr int NL75_TN  = 2048;
constexpr int NL75_MID = 64;
constexpr int NL75_C   = 128;

typedef __attribute__((ext_vector_type(8))) short nl75_bf8;
typedef __attribute__((ext_vector_type(4))) float nl75_f4;

__device__ __forceinline__ unsigned short nl75_f2b(float f) {
  unsigned x = __float_as_uint(f);
  return (unsigned short)((x + 0x7fffu + ((x >> 16) & 1u)) >> 16);
}

__device__ __forceinline__ unsigned int nl75_pkbf16(float lo, float hi) {
  unsigned int r;
  asm("v_cvt_pk_bf16_f32 %0, %1, %2" : "=v"(r) : "v"(lo), "v"(hi));
  return r;
}

__global__ void NonLocalLayer_75771813036638_kernel() {}

// ---------------- projections -> bf16 frag-ready layouts --------------------
// grid (nb, 3, 32), block 256.  thT/phT: [bl][x][m] bf16 (row = 64 shorts).
// g: [bl][m][k] bf16 (natural).
__global__ void nl75_proj(const float* pc, const float* w0, const float* b0,
                          const float* w1, const float* b1, const float* w2,
                          const float* b2, unsigned short* thT,
                          unsigned short* phT, unsigned short* gN, int bOff,
                          int nb) {
  __shared__ float wT[NL75_C][68];
  const int bl = blockIdx.x, pj = blockIdx.y, qt = blockIdx.z;
  const int b = bOff + bl;
  const float* wp = (pj == 0) ? w0 : (pj == 1) ? w1 : w2;
  const float* bp = (pj == 0) ? b0 : (pj == 1) ? b1 : b2;
  const int tid = threadIdx.x;
  for (int i = tid; i < NL75_MID * NL75_C; i += 256)
    wT[i & 127][i >> 7] = wp[i];
  __syncthreads();
  const int lq = tid & 63, mg = tid >> 6;
  const int q = qt * 64 + lq, m0 = mg * 16;
  const float* pcb = pc + (long long)b * NL75_C * NL75_TN + q;
  float acc[16];
#pragma unroll
  for (int i = 0; i < 16; i++) acc[i] = bp[m0 + i];
  for (int c = 0; c < NL75_C; c++) {
    float p = pcb[(long long)c * NL75_TN];
#pragma unroll
    for (int i = 0; i < 16; i++) acc[i] = fmaf(wT[c][m0 + i], p, acc[i]);
  }
  if (pj < 2) {
    unsigned int u[8];
#pragma unroll
    for (int i = 0; i < 8; i++)
      u[i] = nl75_pkbf16(fmaxf(acc[2 * i], 0.0f), fmaxf(acc[2 * i + 1], 0.0f));
    unsigned short* dst =
        (pj == 0 ? thT : phT) + ((size_t)bl * NL75_TN + q) * 64 + m0;
    *reinterpret_cast<uint4*>(dst) = *reinterpret_cast<uint4*>(&u[0]);
    *reinterpret_cast<uint4*>(dst + 8) = *reinterpret_cast<uint4*>(&u[4]);
  } else {
#pragma unroll
    for (int i = 0; i < 16; i++)
      gN[((size_t)bl * NL75_MID + m0 + i) * NL75_TN + q] =
          nl75_f2b(fmaxf(acc[i], 0.0f));
  }
}

// ------------- partial softmax stats (LDS-free, barrier-free) ---------------
// grid (nb, 32*qsplit), block 256.
__global__ void nl75_stats(const unsigned short* thT, const unsigned short* phT,
                           float* Mp, float* Sp, int nb, int qsplit) {
  const int bl = blockIdx.x;
  const int kt = blockIdx.y & 31, qs = blockIdx.y >> 5;
  const int tid = threadIdx.x, lane = tid & 63, w = tid >> 6;
  const int l15 = lane & 15, quad = lane >> 4;
  const int k0 = kt * 64;
  const unsigned short* thB = thT + (size_t)bl * NL75_TN * 64;
  const unsigned short* phB = phT + (size_t)bl * NL75_TN * 64;
  const size_t kr = (size_t)(k0 + w * 16 + l15) * 64;
  const nl75_bf8 b0 = *(const nl75_bf8*)&phB[kr + quad * 8];
  const nl75_bf8 b1 = *(const nl75_bf8*)&phB[kr + 32 + quad * 8];
  float M = -1e30f, S = 0.0f;
  const int qtN = 32 / qsplit, qtBeg = qs * qtN;
  for (int qt = qtBeg; qt < qtBeg + qtN; qt++) {
#pragma unroll
    for (int q16 = 0; q16 < 4; q16++) {
      const size_t qr = (size_t)(qt * 64 + q16 * 16 + l15) * 64;
      const nl75_bf8 a0 = *(const nl75_bf8*)&thB[qr + quad * 8];
      const nl75_bf8 a1 = *(const nl75_bf8*)&thB[qr + 32 + quad * 8];
      nl75_f4 c = {0.0f, 0.0f, 0.0f, 0.0f};
      c = __builtin_amdgcn_mfma_f32_16x16x32_bf16(a0, b0, c, 0, 0, 0);
      c = __builtin_amdgcn_mfma_f32_16x16x32_bf16(a1, b1, c, 0, 0, 0);
      float mx = fmaxf(fmaxf(c[0], c[1]), fmaxf(c[2], c[3]));
      float nM = fmaxf(M, mx);
      float sum = __expf(c[0] - nM) + __expf(c[1] - nM) + __expf(c[2] - nM) +
                  __expf(c[3] - nM);
      S = S * __expf(M - nM) + sum;
      M = nM;
    }
  }
#pragma unroll
  for (int off = 16; off <= 32; off <<= 1) {
    float Mo = __shfl_xor(M, off);
    float So = __shfl_xor(S, off);
    float nM = fmaxf(M, Mo);
    S = S * __expf(M - nM) + So * __expf(Mo - nM);
    M = nM;
  }
  if (quad == 0) {
    const long long base = ((long long)(qs * nb + bl)) * NL75_TN + k0;
    Mp[base + w * 16 + l15] = M;
    Sp[base + w * 16 + l15] = S;
  }
}

// ------------- combine partial stats: grid (nb, 8), one k per thread --------
__global__ void nl75_sred(const float* Mp, const float* Sp, float* mW,
                          float* izW, int nb, int qsplit) {
  const int bl = blockIdx.x;
  const int k = blockIdx.y * 256 + threadIdx.x;
  float M = -1e30f;
  for (int qs = 0; qs < qsplit; qs++)
    M = fmaxf(M, Mp[((size_t)(qs * nb + bl)) * NL75_TN + k]);
  float S = 0.0f;
  for (int qs = 0; qs < qsplit; qs++) {
    size_t idx = ((size_t)(qs * nb + bl)) * NL75_TN + k;
    S += Sp[idx] * __expf(Mp[idx] - M);
  }
  mW[(size_t)bl * NL75_TN + k] = M;
  izW[(size_t)bl * NL75_TN + k] = 1.0f / S;
}

// ------------- attention apply + PV (LDS-free, 2 q-tiles/block) -------------
// grid 1D (16*ksplit*nb), block 256. bl fastest (XCD pinning).
__launch_bounds__(256, 4)
__global__ void nl75_attn(const unsigned short* thT, const unsigned short* phT,
                          const unsigned short* gN, const float* mW,
                          const float* izW, float* yPart, int nb, int ksplit) {
  const int wg = blockIdx.x;
  const int bl = wg % nb;
  const int rest = wg / nb;
  const int qt = rest & 15, ks = rest >> 4;
  const int tid = threadIdx.x, lane = tid & 63, w = tid >> 6;
  const int l15 = lane & 15, quad = lane >> 4;
  const int q0 = qt * 128;
  const unsigned short* thB = thT + (size_t)bl * NL75_TN * 64;
  const unsigned short* phB = phT + (size_t)bl * NL75_TN * 64;
  const unsigned short* gB = gN + (size_t)bl * NL75_MID * NL75_TN;
  const float* mB = mW + (size_t)bl * NL75_TN;
  const float* izB = izW + (size_t)bl * NL75_TN;
  // theta frags for the 2 q-tiles (held across all kt)
  nl75_bf8 aq[2][2];
#pragma unroll
  for (int s = 0; s < 2; s++) {
    const size_t qr = (size_t)(q0 + s * 64 + w * 16 + l15) * 64;
    aq[s][0] = *(const nl75_bf8*)&thB[qr + quad * 8];
    aq[s][1] = *(const nl75_bf8*)&thB[qr + 32 + quad * 8];
  }
  nl75_f4 yacc[2][4];
#pragma unroll
  for (int s = 0; s < 2; s++)
#pragma unroll
    for (int i = 0; i < 4; i++) yacc[s][i] = (nl75_f4){0.0f, 0.0f, 0.0f, 0.0f};
  const int ktN = 32 / ksplit;
  const int ktBeg = ks * ktN, ktEnd = ktBeg + ktN;
  union Frag { nl75_bf8 h; unsigned int u[4]; };
  for (int kt = ktBeg; kt < ktEnd; kt++) {
    const int k0 = kt * 64;
    // QK swapped: lane holds C'[k = k0+t*16+4*quad+r][q = q0+s*64+w*16+l15];
    // exp-scale and pack to bf16 entirely in registers.
    unsigned int pk[2][8];
#pragma unroll
    for (int t = 0; t < 4; t++) {
      const size_t kr = (size_t)(k0 + t * 16 + l15) * 64;
      const nl75_bf8 b0 = *(const nl75_bf8*)&phB[kr + quad * 8];
      const nl75_bf8 b1 = *(const nl75_bf8*)&phB[kr + 32 + quad * 8];
      const nl75_f4 mk = *(const nl75_f4*)&mB[k0 + t * 16 + quad * 4];
      const nl75_f4 zk = *(const nl75_f4*)&izB[k0 + t * 16 + quad * 4];
#pragma unroll
      for (int s = 0; s < 2; s++) {
        nl75_f4 c = {0.0f, 0.0f, 0.0f, 0.0f};
        c = __builtin_amdgcn_mfma_f32_16x16x32_bf16(b0, aq[s][0], c, 0, 0, 0);
        c = __builtin_amdgcn_mfma_f32_16x16x32_bf16(b1, aq[s][1], c, 0, 0, 0);
        pk[s][t * 2 + 0] = nl75_pkbf16(__expf(c[0] - mk[0]) * zk[0],
                                       __expf(c[1] - mk[1]) * zk[1]);
        pk[s][t * 2 + 1] = nl75_pkbf16(__expf(c[2] - mk[2]) * zk[2],
                                       __expf(c[3] - mk[3]) * zk[3]);
      }
    }
    // PV: A-frag = own pk regs; B-frag = g rows with the matching slot
    // relabel: slot 8q+j -> k = 16*(j>>2) + 4*q + (j&3).
#pragma unroll
    for (int mtile = 0; mtile < 4; mtile++) {
      const unsigned short* row = &gB[(size_t)(mtile * 16 + l15) * NL75_TN + k0];
      Frag bg0, bg1;
      *(uint2*)&bg0.u[0] = *(const uint2*)&row[quad * 4];
      *(uint2*)&bg0.u[2] = *(const uint2*)&row[16 + quad * 4];
      *(uint2*)&bg1.u[0] = *(const uint2*)&row[32 + quad * 4];
      *(uint2*)&bg1.u[2] = *(const uint2*)&row[48 + quad * 4];
#pragma unroll
      for (int s = 0; s < 2; s++) {
        Frag a0, a1;
        a0.u[0] = pk[s][0]; a0.u[1] = pk[s][1];
        a0.u[2] = pk[s][2]; a0.u[3] = pk[s][3];
        a1.u[0] = pk[s][4]; a1.u[1] = pk[s][5];
        a1.u[2] = pk[s][6]; a1.u[3] = pk[s][7];
        yacc[s][mtile] = __builtin_amdgcn_mfma_f32_16x16x32_bf16(
            a0.h, bg0.h, yacc[s][mtile], 0, 0, 0);
        yacc[s][mtile] = __builtin_amdgcn_mfma_f32_16x16x32_bf16(
            a1.h, bg1.h, yacc[s][mtile], 0, 0, 0);
      }
    }
  }
  // direct float4 y-store: lane holds y[m = mtile*16+l15][q = q0+s*64+w*16+quad*4 + r]
  float* yB = yPart + ((size_t)(ks * nb + bl) * NL75_MID) * NL75_TN;
#pragma unroll
  for (int s = 0; s < 2; s++)
#pragma unroll
    for (int mtile = 0; mtile < 4; mtile++) {
      float4 v = make_float4(yacc[s][mtile][0], yacc[s][mtile][1],
                             yacc[s][mtile][2], yacc[s][mtile][3]);
      *(float4*)&yB[(size_t)(mtile * 16 + l15) * NL75_TN + q0 + s * 64 +
                    w * 16 + quad * 4] = v;
    }
}

// ------- streaming ksplit-reduction: y = sum_ks yPart[ks] -------------------
__global__ void nl75_yred(const float* yPart, float* y, int nb, int ksplit) {
  const size_t tot = (size_t)nb * NL75_MID * NL75_TN / 4;
  const size_t stride = tot;
  const float4* src = (const float4*)yPart;
  float4* dst = (float4*)y;
  for (size_t i = (size_t)blockIdx.x * 256 + threadIdx.x; i < tot;
       i += (size_t)gridDim.x * 256) {
    float4 a = src[i];
    for (int ks = 1; ks < ksplit; ks++) {
      float4 b = src[(size_t)ks * stride + i];
      a.x += b.x; a.y += b.y; a.z += b.z; a.w += b.w;
    }
    dst[i] = a;
  }
}

// ------- fused refine GEMM + scatter + residual -----------------------------
// grid (nb, 16, 4), block 256 (bl fastest for XCD-local y/pc reuse).
__global__ void nl75_refsc(const float* yPart, const float* rW,
                           const float* rB, const float* pc, float* outP,
                           int bOff, int nb, int ksplit) {
  __shared__ float rwS[32][66];
  __shared__ float yS[NL75_MID][132];
  const int bl = blockIdx.x, cg = blockIdx.y, t = blockIdx.z;
  const int b = bOff + bl, c0 = cg * 8, tid = threadIdx.x;
  for (int i = tid; i < 32 * NL75_MID; i += 256) {
    int oh = i >> 6, m = i & 63;
    rwS[oh][m] = rW[(long long)(t * 32 + oh) * NL75_MID + m];
  }
  for (int i = tid; i < NL75_MID * 128; i += 256) {
    int m = i >> 7, qi = i & 127;
    int i16 = qi >> 3, cl = qi & 7;
    long long off = (long long)m * NL75_TN + i16 * 128 + c0 + cl;
    float v = 0.0f;
    for (int ks = 0; ks < ksplit; ks++)
      v += yPart[((long long)(ks * nb + bl) * NL75_MID) * NL75_TN + off];
    yS[m][qi] = v;
  }
  __syncthreads();
  const int oh0 = (tid >> 5) * 4;
  const int q4 = (tid & 31) * 4;
  float acc[4][4];
#pragma unroll
  for (int i = 0; i < 4; i++) {
    float bias = rB[t * 32 + oh0 + i];
#pragma unroll
    for (int j = 0; j < 4; j++) acc[i][j] = bias;
  }
  for (int m = 0; m < NL75_MID; m++) {
    float yv[4];
#pragma unroll
    for (int j = 0; j < 4; j++) yv[j] = yS[m][q4 + j];
#pragma unroll
    for (int i = 0; i < 4; i++) {
      float w = rwS[oh0 + i][m];
#pragma unroll
      for (int j = 0; j < 4; j++) acc[i][j] = fmaf(w, yv[j], acc[i][j]);
    }
  }
#pragma unroll
  for (int i = 0; i < 4; i++) {
    int oh = oh0 + i;
#pragma unroll
    for (int j = 0; j < 4; j++) {
      int qi = q4 + j;
      int i16 = qi >> 3, cl = qi & 7;
      int n = oh * 16 + i16;
      long long idx = (((long long)b * 128 + c0 + cl) * 4 + t) * 512 + n;
      outP[idx] = fmaxf(acc[i][j], 0.0f) + pc[idx];
    }
  }
}

extern "C" void kernel_launch(void* const* d_in, const int* in_sizes, int n_in,
                              void* d_out, int out_size, void* d_ws, size_t ws_size,
                              hipStream_t stream) {
  const float* pc = (const float*)d_in[0];
  const float* tw = (const float*)d_in[1];
  const float* tb = (const float*)d_in[2];
  const float* pw = (const float*)d_in[3];
  const float* pb = (const float*)d_in[4];
  const float* gw = (const float*)d_in[5];
  const float* gb = (const float*)d_in[6];
  const float* rw = (const float*)d_in[7];
  const float* rb = (const float*)d_in[8];
  float* out = (float*)d_out;

  const size_t yPB = (size_t)NL75_MID * NL75_TN;             // floats
  const size_t bfB8 = 3ull * 8 * NL75_TN * 64 * 2;           // bf16 proj, nb=8
  const size_t base8 = bfB8 + 2ull * 8 * NL75_TN * 4;        // + mW/izW
  auto need = [&](int qs, int ks, int yr) -> size_t {
    return base8 + (2ull * qs * 8 * NL75_TN + (size_t)ks * 8 * yPB +
                    (size_t)yr * 8 * yPB) * 4;
  };
  const size_t needMid = base8 + 8ull * yPB * 4;
  const size_t needMin =
      3ull * NL75_TN * 64 * 2 + 2ull * NL75_TN * 4 + yPB * 4;
  (void)needMin;

  int nb, qsplit, ksplit;
  bool alias, yred;
  if (ws_size >= need(8, 8, 1)) {
    nb = 8; qsplit = 8; ksplit = 8; alias = false; yred = true;
  } else if (ws_size >= need(8, 4, 1)) {
    nb = 8; qsplit = 8; ksplit = 4; alias = false; yred = true;
  } else if (ws_size >= need(4, 4, 1)) {
    nb = 8; qsplit = 4; ksplit = 4; alias = false; yred = true;
  } else if (ws_size >= need(4, 4, 0)) {
    nb = 8; qsplit = 4; ksplit = 4; alias = false; yred = false;
  } else if (ws_size >= needMid) {
    nb = 8; qsplit = 1; ksplit = 1; alias = true; yred = false;
  } else {
    nb = 1; qsplit = 1; ksplit = 1; alias = true; yred = false;
  }
  const int nloop = 8 / nb;

  unsigned short* thT = (unsigned short*)d_ws;
  unsigned short* phT = thT + (size_t)nb * NL75_TN * 64;
  unsigned short* gN = phT + (size_t)nb * NL75_TN * 64;
  float* mW = (float*)(gN + (size_t)nb * NL75_MID * NL75_TN);
  float* izW = mW + (size_t)nb * NL75_TN;
  float *Mp, *Sp, *yPart, *yFull;
  if (alias) {
    Mp = mW; Sp = izW;
    yPart = izW + (size_t)nb * NL75_TN;
    yFull = yPart;
  } else {
    Mp = izW + (size_t)nb * NL75_TN;
    Sp = Mp + (size_t)qsplit * nb * NL75_TN;
    yPart = Sp + (size_t)qsplit * nb * NL75_TN;
    yFull = yPart + (size_t)ksplit * nb * yPB;
  }

  for (int l = 0; l < nloop; l++) {
    const int bOff = l * nb;
    nl75_proj<<<dim3(nb, 3, 32), 256, 0, stream>>>(pc, tw, tb, pw, pb, gw, gb,
                                                   thT, phT, gN, bOff, nb);
    nl75_stats<<<dim3(nb, 32 * qsplit), 256, 0, stream>>>(thT, phT, Mp, Sp,
                                                          nb, qsplit);
    nl75_sred<<<dim3(nb, 8), 256, 0, stream>>>(Mp, Sp, mW, izW, nb, qsplit);
    nl75_attn<<<dim3(16 * ksplit * nb), 256, 0, stream>>>(thT, phT, gN, mW,
                                                          izW, yPart, nb,
                                                          ksplit);
    if (yred) {
      nl75_yred<<<dim3(1024), 256, 0, stream>>>(yPart, yFull, nb, ksplit);
      nl75_refsc<<<dim3(nb, 16, 4), 256, 0, stream>>>(yFull, rw, rb, pc, out,
                                                      bOff, nb, 1);
    } else {
      nl75_refsc<<<dim3(nb, 16, 4), 256, 0, stream>>>(yPart, rw, rb, pc, out,
                                                      bOff, nb, ksplit);
    }
  }
}

// Round 4
// 158.439 us; speedup vs baseline: 1.7389x; 1.3453x over previous
//
#include <hip/hip_runtime.h>

// NonLocalLayer  B=8, C=128, MID=64, OUT=128, T=4, N=512, TN=2048
// R22: R21 + double-buffered LDS staging via global_load_lds for attn (phi,g)
// and stats (theta). LDS dest linear, global SOURCE pre-swizzled with the
// involution col ^= ((row&7)<<3) (shorts, 16B-granular); all ds_reads apply
// the same XOR. One barrier per kt. proj/sred/yred/refsc unchanged.

constexpr int NL75_TN  = 2048;
constexpr int NL75_MID = 64;
constexpr int NL75_C   = 128;

typedef __attribute__((ext_vector_type(8))) short nl75_bf8;
typedef __attribute__((ext_vector_type(4))) float nl75_f4;

__device__ __forceinline__ unsigned short nl75_f2b(float f) {
  unsigned x = __float_as_uint(f);
  return (unsigned short)((x + 0x7fffu + ((x >> 16) & 1u)) >> 16);
}

__device__ __forceinline__ unsigned int nl75_pkbf16(float lo, float hi) {
  unsigned int r;
  asm("v_cvt_pk_bf16_f32 %0, %1, %2" : "=v"(r) : "v"(lo), "v"(hi));
  return r;
}

typedef const __attribute__((address_space(1))) unsigned int* nl75_gp;
typedef __attribute__((address_space(3))) unsigned int* nl75_lp;
__device__ __forceinline__ void nl75_gld16(const void* g, void* l) {
  __builtin_amdgcn_global_load_lds((nl75_gp)g, (nl75_lp)l, 16, 0, 0);
}

// stage a 64x64 bf16 tile into LDS: lds[row][c] = src[row][c ^ ((row&7)<<3)]
// (linear LDS dest = wave-uniform base + lane*16; swizzle on the SOURCE).
__device__ __forceinline__ void nl75_stage64(const unsigned short* src,
                                             size_t pitch, unsigned short* lds,
                                             int tid) {
  const int w = tid >> 6, lane = tid & 63;
#pragma unroll
  for (int r = 0; r < 2; r++) {
    const int slot = r * 256 + w * 64 + lane;
    const int row = slot >> 3, x = slot & 7;
    const unsigned short* s =
        src + (size_t)row * pitch + ((x * 8) ^ ((row & 7) << 3));
    nl75_gld16(s, lds + (size_t)(r * 256 + w * 64) * 8);
  }
}

__global__ void NonLocalLayer_75771813036638_kernel() {}

// ---------------- projections -> bf16 frag-ready layouts (unchanged) --------
// grid (nb, 3, 32), block 256.  thT/phT: [bl][x][m] bf16. g: [bl][m][k] bf16.
__global__ void nl75_proj(const float* pc, const float* w0, const float* b0,
                          const float* w1, const float* b1, const float* w2,
                          const float* b2, unsigned short* thT,
                          unsigned short* phT, unsigned short* gN, int bOff,
                          int nb) {
  __shared__ float wT[NL75_C][68];
  const int bl = blockIdx.x, pj = blockIdx.y, qt = blockIdx.z;
  const int b = bOff + bl;
  const float* wp = (pj == 0) ? w0 : (pj == 1) ? w1 : w2;
  const float* bp = (pj == 0) ? b0 : (pj == 1) ? b1 : b2;
  const int tid = threadIdx.x;
  for (int i = tid; i < NL75_MID * NL75_C; i += 256)
    wT[i & 127][i >> 7] = wp[i];
  __syncthreads();
  const int lq = tid & 63, mg = tid >> 6;
  const int q = qt * 64 + lq, m0 = mg * 16;
  const float* pcb = pc + (long long)b * NL75_C * NL75_TN + q;
  float acc[16];
#pragma unroll
  for (int i = 0; i < 16; i++) acc[i] = bp[m0 + i];
  for (int c = 0; c < NL75_C; c++) {
    float p = pcb[(long long)c * NL75_TN];
#pragma unroll
    for (int i = 0; i < 16; i++) acc[i] = fmaf(wT[c][m0 + i], p, acc[i]);
  }
  if (pj < 2) {
    unsigned int u[8];
#pragma unroll
    for (int i = 0; i < 8; i++)
      u[i] = nl75_pkbf16(fmaxf(acc[2 * i], 0.0f), fmaxf(acc[2 * i + 1], 0.0f));
    unsigned short* dst =
        (pj == 0 ? thT : phT) + ((size_t)bl * NL75_TN + q) * 64 + m0;
    *reinterpret_cast<uint4*>(dst) = *reinterpret_cast<uint4*>(&u[0]);
    *reinterpret_cast<uint4*>(dst + 8) = *reinterpret_cast<uint4*>(&u[4]);
  } else {
#pragma unroll
    for (int i = 0; i < 16; i++)
      gN[((size_t)bl * NL75_MID + m0 + i) * NL75_TN + q] =
          nl75_f2b(fmaxf(acc[i], 0.0f));
  }
}

// ------------- partial softmax stats (dbuf-LDS theta, MFMA QK) --------------
// grid (nb, 32*qsplit), block 256. LDS 16 KB.
__global__ void nl75_stats(const unsigned short* thT, const unsigned short* phT,
                           float* Mp, float* Sp, int nb, int qsplit) {
  __shared__ unsigned short thL[2][64 * 64];
  const int bl = blockIdx.x;
  const int kt = blockIdx.y & 31, qs = blockIdx.y >> 5;
  const int tid = threadIdx.x, lane = tid & 63, w = tid >> 6;
  const int l15 = lane & 15, quad = lane >> 4;
  const int k0 = kt * 64;
  const unsigned short* thB = thT + (size_t)bl * NL75_TN * 64;
  const unsigned short* phB = phT + (size_t)bl * NL75_TN * 64;
  const size_t kr = (size_t)(k0 + w * 16 + l15) * 64;
  const nl75_bf8 b0 = *(const nl75_bf8*)&phB[kr + quad * 8];
  const nl75_bf8 b1 = *(const nl75_bf8*)&phB[kr + 32 + quad * 8];
  const int qtN = 32 / qsplit, qtBeg = qs * qtN;
  nl75_stage64(thB + (size_t)(qtBeg * 64) * 64, 64, thL[0], tid);
  __syncthreads();
  float M = -1e30f, S = 0.0f;
  for (int qt = qtBeg; qt < qtBeg + qtN; qt++) {
    const int cur = (qt - qtBeg) & 1;
    if (qt + 1 < qtBeg + qtN)
      nl75_stage64(thB + (size_t)((qt + 1) * 64) * 64, 64, thL[cur ^ 1], tid);
#pragma unroll
    for (int q16 = 0; q16 < 4; q16++) {
      const int qr = q16 * 16 + l15;
      const int sw = (qr & 7) << 3;
      const nl75_bf8 a0 = *(const nl75_bf8*)&thL[cur][qr * 64 + ((quad * 8) ^ sw)];
      const nl75_bf8 a1 =
          *(const nl75_bf8*)&thL[cur][qr * 64 + ((32 + quad * 8) ^ sw)];
      nl75_f4 c = {0.0f, 0.0f, 0.0f, 0.0f};
      c = __builtin_amdgcn_mfma_f32_16x16x32_bf16(a0, b0, c, 0, 0, 0);
      c = __builtin_amdgcn_mfma_f32_16x16x32_bf16(a1, b1, c, 0, 0, 0);
      float mx = fmaxf(fmaxf(c[0], c[1]), fmaxf(c[2], c[3]));
      float nM = fmaxf(M, mx);
      float sum = __expf(c[0] - nM) + __expf(c[1] - nM) + __expf(c[2] - nM) +
                  __expf(c[3] - nM);
      S = S * __expf(M - nM) + sum;
      M = nM;
    }
    __syncthreads();
  }
#pragma unroll
  for (int off = 16; off <= 32; off <<= 1) {
    float Mo = __shfl_xor(M, off);
    float So = __shfl_xor(S, off);
    float nM = fmaxf(M, Mo);
    S = S * __expf(M - nM) + So * __expf(Mo - nM);
    M = nM;
  }
  if (quad == 0) {
    const long long base = ((long long)(qs * nb + bl)) * NL75_TN + k0;
    Mp[base + w * 16 + l15] = M;
    Sp[base + w * 16 + l15] = S;
  }
}

// ------------- combine partial stats: grid (nb, 8) --------------------------
__global__ void nl75_sred(const float* Mp, const float* Sp, float* mW,
                          float* izW, int nb, int qsplit) {
  const int bl = blockIdx.x;
  const int k = blockIdx.y * 256 + threadIdx.x;
  float M = -1e30f;
  for (int qs = 0; qs < qsplit; qs++)
    M = fmaxf(M, Mp[((size_t)(qs * nb + bl)) * NL75_TN + k]);
  float S = 0.0f;
  for (int qs = 0; qs < qsplit; qs++) {
    size_t idx = ((size_t)(qs * nb + bl)) * NL75_TN + k;
    S += Sp[idx] * __expf(Mp[idx] - M);
  }
  mW[(size_t)bl * NL75_TN + k] = M;
  izW[(size_t)bl * NL75_TN + k] = 1.0f / S;
}

// ------------- attention apply + PV (dbuf-LDS phi/g, 2 q-tiles/block) -------
// grid 1D (16*ksplit*nb), block 256, bl fastest (XCD pinning). LDS 32 KB.
__global__ void nl75_attn(const unsigned short* thT, const unsigned short* phT,
                          const unsigned short* gN, const float* mW,
                          const float* izW, float* yPart, int nb, int ksplit) {
  __shared__ unsigned short phL[2][64 * 64];
  __shared__ unsigned short gL[2][64 * 64];
  const int wg = blockIdx.x;
  const int bl = wg % nb;
  const int rest = wg / nb;
  const int qt = rest & 15, ks = rest >> 4;
  const int tid = threadIdx.x, lane = tid & 63, w = tid >> 6;
  const int l15 = lane & 15, quad = lane >> 4;
  const int q0 = qt * 128;
  const unsigned short* thB = thT + (size_t)bl * NL75_TN * 64;
  const unsigned short* phB = phT + (size_t)bl * NL75_TN * 64;
  const unsigned short* gB = gN + (size_t)bl * NL75_MID * NL75_TN;
  const float* mB = mW + (size_t)bl * NL75_TN;
  const float* izB = izW + (size_t)bl * NL75_TN;
  const int ktN = 32 / ksplit;
  const int ktBeg = ks * ktN, ktEnd = ktBeg + ktN;
  // prologue: stage first tiles
  nl75_stage64(phB + (size_t)(ktBeg * 64) * 64, 64, phL[0], tid);
  nl75_stage64(gB + ktBeg * 64, NL75_TN, gL[0], tid);
  // theta frags for the 2 q-tiles (global, linear layout, loaded once)
  nl75_bf8 aq[2][2];
#pragma unroll
  for (int s = 0; s < 2; s++) {
    const size_t qr = (size_t)(q0 + s * 64 + w * 16 + l15) * 64;
    aq[s][0] = *(const nl75_bf8*)&thB[qr + quad * 8];
    aq[s][1] = *(const nl75_bf8*)&thB[qr + 32 + quad * 8];
  }
  nl75_f4 yacc[2][4];
#pragma unroll
  for (int s = 0; s < 2; s++)
#pragma unroll
    for (int i = 0; i < 4; i++) yacc[s][i] = (nl75_f4){0.0f, 0.0f, 0.0f, 0.0f};
  __syncthreads();
  union Frag { nl75_bf8 h; unsigned int u[4]; };
  for (int kt = ktBeg; kt < ktEnd; kt++) {
    const int cur = (kt - ktBeg) & 1;
    const int k0 = kt * 64;
    if (kt + 1 < ktEnd) {
      nl75_stage64(phB + (size_t)((kt + 1) * 64) * 64, 64, phL[cur ^ 1], tid);
      nl75_stage64(gB + (kt + 1) * 64, NL75_TN, gL[cur ^ 1], tid);
    }
    // QK swapped: lane holds C'[k = k0+t*16+4*quad+r][q = q0+s*64+w*16+l15]
    unsigned int pk[2][8];
#pragma unroll
    for (int t = 0; t < 4; t++) {
      const int krr = t * 16 + l15;
      const int sw = (krr & 7) << 3;
      const nl75_bf8 b0 =
          *(const nl75_bf8*)&phL[cur][krr * 64 + ((quad * 8) ^ sw)];
      const nl75_bf8 b1 =
          *(const nl75_bf8*)&phL[cur][krr * 64 + ((32 + quad * 8) ^ sw)];
      const nl75_f4 mk = *(const nl75_f4*)&mB[k0 + t * 16 + quad * 4];
      const nl75_f4 zk = *(const nl75_f4*)&izB[k0 + t * 16 + quad * 4];
#pragma unroll
      for (int s = 0; s < 2; s++) {
        nl75_f4 c = {0.0f, 0.0f, 0.0f, 0.0f};
        c = __builtin_amdgcn_mfma_f32_16x16x32_bf16(b0, aq[s][0], c, 0, 0, 0);
        c = __builtin_amdgcn_mfma_f32_16x16x32_bf16(b1, aq[s][1], c, 0, 0, 0);
        pk[s][t * 2 + 0] = nl75_pkbf16(__expf(c[0] - mk[0]) * zk[0],
                                       __expf(c[1] - mk[1]) * zk[1]);
        pk[s][t * 2 + 1] = nl75_pkbf16(__expf(c[2] - mk[2]) * zk[2],
                                       __expf(c[3] - mk[3]) * zk[3]);
      }
    }
    // PV: A-frag = own pk regs; B-frag = g rows with matching slot relabel:
    // slot 8q+j -> k = 16*(j>>2) + 4*q + (j&3).
#pragma unroll
    for (int mtile = 0; mtile < 4; mtile++) {
      const int m = mtile * 16 + l15;
      const int sw = (m & 7) << 3;
      const unsigned short* row = &gL[cur][m * 64];
      Frag bg0, bg1;
      *(uint2*)&bg0.u[0] = *(const uint2*)&row[(quad * 4) ^ sw];
      *(uint2*)&bg0.u[2] = *(const uint2*)&row[(16 + quad * 4) ^ sw];
      *(uint2*)&bg1.u[0] = *(const uint2*)&row[(32 + quad * 4) ^ sw];
      *(uint2*)&bg1.u[2] = *(const uint2*)&row[(48 + quad * 4) ^ sw];
#pragma unroll
      for (int s = 0; s < 2; s++) {
        Frag a0, a1;
        a0.u[0] = pk[s][0]; a0.u[1] = pk[s][1];
        a0.u[2] = pk[s][2]; a0.u[3] = pk[s][3];
        a1.u[0] = pk[s][4]; a1.u[1] = pk[s][5];
        a1.u[2] = pk[s][6]; a1.u[3] = pk[s][7];
        yacc[s][mtile] = __builtin_amdgcn_mfma_f32_16x16x32_bf16(
            a0.h, bg0.h, yacc[s][mtile], 0, 0, 0);
        yacc[s][mtile] = __builtin_amdgcn_mfma_f32_16x16x32_bf16(
            a1.h, bg1.h, yacc[s][mtile], 0, 0, 0);
      }
    }
    __syncthreads();
  }
  // direct float4 y-store: lane holds y[m][q0 + s*64 + w*16 + quad*4 + r]
  float* yB = yPart + ((size_t)(ks * nb + bl) * NL75_MID) * NL75_TN;
#pragma unroll
  for (int s = 0; s < 2; s++)
#pragma unroll
    for (int mtile = 0; mtile < 4; mtile++) {
      float4 v = make_float4(yacc[s][mtile][0], yacc[s][mtile][1],
                             yacc[s][mtile][2], yacc[s][mtile][3]);
      *(float4*)&yB[(size_t)(mtile * 16 + l15) * NL75_TN + q0 + s * 64 +
                    w * 16 + quad * 4] = v;
    }
}

// ------- streaming ksplit-reduction: y = sum_ks yPart[ks] -------------------
__global__ void nl75_yred(const float* yPart, float* y, int nb, int ksplit) {
  const size_t tot = (size_t)nb * NL75_MID * NL75_TN / 4;
  const size_t stride = tot;
  const float4* src = (const float4*)yPart;
  float4* dst = (float4*)y;
  for (size_t i = (size_t)blockIdx.x * 256 + threadIdx.x; i < tot;
       i += (size_t)gridDim.x * 256) {
    float4 a = src[i];
    for (int ks = 1; ks < ksplit; ks++) {
      float4 b = src[(size_t)ks * stride + i];
      a.x += b.x; a.y += b.y; a.z += b.z; a.w += b.w;
    }
    dst[i] = a;
  }
}

// ------- fused refine GEMM + scatter + residual (unchanged) -----------------
__global__ void nl75_refsc(const float* yPart, const float* rW,
                           const float* rB, const float* pc, float* outP,
                           int bOff, int nb, int ksplit) {
  __shared__ float rwS[32][66];
  __shared__ float yS[NL75_MID][132];
  const int bl = blockIdx.x, cg = blockIdx.y, t = blockIdx.z;
  const int b = bOff + bl, c0 = cg * 8, tid = threadIdx.x;
  for (int i = tid; i < 32 * NL75_MID; i += 256) {
    int oh = i >> 6, m = i & 63;
    rwS[oh][m] = rW[(long long)(t * 32 + oh) * NL75_MID + m];
  }
  for (int i = tid; i < NL75_MID * 128; i += 256) {
    int m = i >> 7, qi = i & 127;
    int i16 = qi >> 3, cl = qi & 7;
    long long off = (long long)m * NL75_TN + i16 * 128 + c0 + cl;
    float v = 0.0f;
    for (int ks = 0; ks < ksplit; ks++)
      v += yPart[((long long)(ks * nb + bl) * NL75_MID) * NL75_TN + off];
    yS[m][qi] = v;
  }
  __syncthreads();
  const int oh0 = (tid >> 5) * 4;
  const int q4 = (tid & 31) * 4;
  float acc[4][4];
#pragma unroll
  for (int i = 0; i < 4; i++) {
    float bias = rB[t * 32 + oh0 + i];
#pragma unroll
    for (int j = 0; j < 4; j++) acc[i][j] = bias;
  }
  for (int m = 0; m < NL75_MID; m++) {
    float yv[4];
#pragma unroll
    for (int j = 0; j < 4; j++) yv[j] = yS[m][q4 + j];
#pragma unroll
    for (int i = 0; i < 4; i++) {
      float w = rwS[oh0 + i][m];
#pragma unroll
      for (int j = 0; j < 4; j++) acc[i][j] = fmaf(w, yv[j], acc[i][j]);
    }
  }
#pragma unroll
  for (int i = 0; i < 4; i++) {
    int oh = oh0 + i;
#pragma unroll
    for (int j = 0; j < 4; j++) {
      int qi = q4 + j;
      int i16 = qi >> 3, cl = qi & 7;
      int n = oh * 16 + i16;
      long long idx = (((long long)b * 128 + c0 + cl) * 4 + t) * 512 + n;
      outP[idx] = fmaxf(acc[i][j], 0.0f) + pc[idx];
    }
  }
}

extern "C" void kernel_launch(void* const* d_in, const int* in_sizes, int n_in,
                              void* d_out, int out_size, void* d_ws, size_t ws_size,
                              hipStream_t stream) {
  const float* pc = (const float*)d_in[0];
  const float* tw = (const float*)d_in[1];
  const float* tb = (const float*)d_in[2];
  const float* pw = (const float*)d_in[3];
  const float* pb = (const float*)d_in[4];
  const float* gw = (const float*)d_in[5];
  const float* gb = (const float*)d_in[6];
  const float* rw = (const float*)d_in[7];
  const float* rb = (const float*)d_in[8];
  float* out = (float*)d_out;

  const size_t yPB = (size_t)NL75_MID * NL75_TN;             // floats
  const size_t bfB8 = 3ull * 8 * NL75_TN * 64 * 2;           // bf16 proj, nb=8
  const size_t base8 = bfB8 + 2ull * 8 * NL75_TN * 4;        // + mW/izW
  auto need = [&](int qs, int ks, int yr) -> size_t {
    return base8 + (2ull * qs * 8 * NL75_TN + (size_t)ks * 8 * yPB +
                    (size_t)yr * 8 * yPB) * 4;
  };
  const size_t needMid = base8 + 8ull * yPB * 4;

  int nb, qsplit, ksplit;
  bool alias, yred;
  if (ws_size >= need(8, 8, 1)) {
    nb = 8; qsplit = 8; ksplit = 8; alias = false; yred = true;
  } else if (ws_size >= need(8, 4, 1)) {
    nb = 8; qsplit = 8; ksplit = 4; alias = false; yred = true;
  } else if (ws_size >= need(4, 4, 1)) {
    nb = 8; qsplit = 4; ksplit = 4; alias = false; yred = true;
  } else if (ws_size >= need(4, 4, 0)) {
    nb = 8; qsplit = 4; ksplit = 4; alias = false; yred = false;
  } else if (ws_size >= needMid) {
    nb = 8; qsplit = 1; ksplit = 1; alias = true; yred = false;
  } else {
    nb = 1; qsplit = 1; ksplit = 1; alias = true; yred = false;
  }
  const int nloop = 8 / nb;

  unsigned short* thT = (unsigned short*)d_ws;
  unsigned short* phT = thT + (size_t)nb * NL75_TN * 64;
  unsigned short* gN = phT + (size_t)nb * NL75_TN * 64;
  float* mW = (float*)(gN + (size_t)nb * NL75_MID * NL75_TN);
  float* izW = mW + (size_t)nb * NL75_TN;
  float *Mp, *Sp, *yPart, *yFull;
  if (alias) {
    Mp = mW; Sp = izW;
    yPart = izW + (size_t)nb * NL75_TN;
    yFull = yPart;
  } else {
    Mp = izW + (size_t)nb * NL75_TN;
    Sp = Mp + (size_t)qsplit * nb * NL75_TN;
    yPart = Sp + (size_t)qsplit * nb * NL75_TN;
    yFull = yPart + (size_t)ksplit * nb * yPB;
  }

  for (int l = 0; l < nloop; l++) {
    const int bOff = l * nb;
    nl75_proj<<<dim3(nb, 3, 32), 256, 0, stream>>>(pc, tw, tb, pw, pb, gw, gb,
                                                   thT, phT, gN, bOff, nb);
    nl75_stats<<<dim3(nb, 32 * qsplit), 256, 0, stream>>>(thT, phT, Mp, Sp,
                                                          nb, qsplit);
    nl75_sred<<<dim3(nb, 8), 256, 0, stream>>>(Mp, Sp, mW, izW, nb, qsplit);
    nl75_attn<<<dim3(16 * ksplit * nb), 256, 0, stream>>>(thT, phT, gN, mW,
                                                          izW, yPart, nb,
                                                          ksplit);
    if (yred) {
      nl75_yred<<<dim3(1024), 256, 0, stream>>>(yPart, yFull, nb, ksplit);
      nl75_refsc<<<dim3(nb, 16, 4), 256, 0, stream>>>(yFull, rw, rb, pc, out,
                                                      bOff, nb, 1);
    } else {
      nl75_refsc<<<dim3(nb, 16, 4), 256, 0, stream>>>(yPart, rw, rb, pc, out,
                                                      bOff, nb, ksplit);
    }
  }
}

// Round 5
// 144.223 us; speedup vs baseline: 1.9103x; 1.0986x over previous
//
#include <hip/hip_runtime.h>

// NonLocalLayer  B=8, C=128, MID=64, OUT=128, T=4, N=512, TN=2048
// R23: R22 + (a) refsc coalesced epilogue via LDS transpose (float4 out/pc,
// float4 y staging on ksplit==1 path), (b) base-2 softmax fold: sred emits
// ek = M*log2e + log2(S), attn does P = exp2(fma(c, log2e, -ek)) -- 2 VALU
// ops/score, no mT/izT staging, (c) s_setprio(1) around MFMA compute in
// attn/stats. Everything else unchanged from R22.

constexpr int NL75_TN  = 2048;
constexpr int NL75_MID = 64;
constexpr int NL75_C   = 128;
constexpr float NL75_L2E = 1.4426950408889634f;

typedef __attribute__((ext_vector_type(8))) short nl75_bf8;
typedef __attribute__((ext_vector_type(4))) float nl75_f4;

__device__ __forceinline__ unsigned short nl75_f2b(float f) {
  unsigned x = __float_as_uint(f);
  return (unsigned short)((x + 0x7fffu + ((x >> 16) & 1u)) >> 16);
}

__device__ __forceinline__ unsigned int nl75_pkbf16(float lo, float hi) {
  unsigned int r;
  asm("v_cvt_pk_bf16_f32 %0, %1, %2" : "=v"(r) : "v"(lo), "v"(hi));
  return r;
}

__device__ __forceinline__ float nl75_exp2(float x) {
  float r;
  asm("v_exp_f32 %0, %1" : "=v"(r) : "v"(x));
  return r;
}

typedef const __attribute__((address_space(1))) unsigned int* nl75_gp;
typedef __attribute__((address_space(3))) unsigned int* nl75_lp;
__device__ __forceinline__ void nl75_gld16(const void* g, void* l) {
  __builtin_amdgcn_global_load_lds((nl75_gp)g, (nl75_lp)l, 16, 0, 0);
}

// stage a 64x64 bf16 tile into LDS: lds[row][c] = src[row][c ^ ((row&7)<<3)]
// (linear LDS dest = wave-uniform base + lane*16; swizzle on the SOURCE).
__device__ __forceinline__ void nl75_stage64(const unsigned short* src,
                                             size_t pitch, unsigned short* lds,
                                             int tid) {
  const int w = tid >> 6, lane = tid & 63;
#pragma unroll
  for (int r = 0; r < 2; r++) {
    const int slot = r * 256 + w * 64 + lane;
    const int row = slot >> 3, x = slot & 7;
    const unsigned short* s =
        src + (size_t)row * pitch + ((x * 8) ^ ((row & 7) << 3));
    nl75_gld16(s, lds + (size_t)(r * 256 + w * 64) * 8);
  }
}

__global__ void NonLocalLayer_75771813036638_kernel() {}

// ---------------- projections -> bf16 frag-ready layouts (unchanged) --------
// grid (nb, 3, 32), block 256.  thT/phT: [bl][x][m] bf16. g: [bl][m][k] bf16.
__global__ void nl75_proj(const float* pc, const float* w0, const float* b0,
                          const float* w1, const float* b1, const float* w2,
                          const float* b2, unsigned short* thT,
                          unsigned short* phT, unsigned short* gN, int bOff,
                          int nb) {
  __shared__ float wT[NL75_C][68];
  const int bl = blockIdx.x, pj = blockIdx.y, qt = blockIdx.z;
  const int b = bOff + bl;
  const float* wp = (pj == 0) ? w0 : (pj == 1) ? w1 : w2;
  const float* bp = (pj == 0) ? b0 : (pj == 1) ? b1 : b2;
  const int tid = threadIdx.x;
  for (int i = tid; i < NL75_MID * NL75_C; i += 256)
    wT[i & 127][i >> 7] = wp[i];
  __syncthreads();
  const int lq = tid & 63, mg = tid >> 6;
  const int q = qt * 64 + lq, m0 = mg * 16;
  const float* pcb = pc + (long long)b * NL75_C * NL75_TN + q;
  float acc[16];
#pragma unroll
  for (int i = 0; i < 16; i++) acc[i] = bp[m0 + i];
  for (int c = 0; c < NL75_C; c++) {
    float p = pcb[(long long)c * NL75_TN];
#pragma unroll
    for (int i = 0; i < 16; i++) acc[i] = fmaf(wT[c][m0 + i], p, acc[i]);
  }
  if (pj < 2) {
    unsigned int u[8];
#pragma unroll
    for (int i = 0; i < 8; i++)
      u[i] = nl75_pkbf16(fmaxf(acc[2 * i], 0.0f), fmaxf(acc[2 * i + 1], 0.0f));
    unsigned short* dst =
        (pj == 0 ? thT : phT) + ((size_t)bl * NL75_TN + q) * 64 + m0;
    *reinterpret_cast<uint4*>(dst) = *reinterpret_cast<uint4*>(&u[0]);
    *reinterpret_cast<uint4*>(dst + 8) = *reinterpret_cast<uint4*>(&u[4]);
  } else {
#pragma unroll
    for (int i = 0; i < 16; i++)
      gN[((size_t)bl * NL75_MID + m0 + i) * NL75_TN + q] =
          nl75_f2b(fmaxf(acc[i], 0.0f));
  }
}

// ------------- partial softmax stats (dbuf-LDS theta, MFMA QK) --------------
// grid (nb, 32*qsplit), block 256. LDS 16 KB.
__global__ void nl75_stats(const unsigned short* thT, const unsigned short* phT,
                           float* Mp, float* Sp, int nb, int qsplit) {
  __shared__ unsigned short thL[2][64 * 64];
  const int bl = blockIdx.x;
  const int kt = blockIdx.y & 31, qs = blockIdx.y >> 5;
  const int tid = threadIdx.x, lane = tid & 63, w = tid >> 6;
  const int l15 = lane & 15, quad = lane >> 4;
  const int k0 = kt * 64;
  const unsigned short* thB = thT + (size_t)bl * NL75_TN * 64;
  const unsigned short* phB = phT + (size_t)bl * NL75_TN * 64;
  const size_t kr = (size_t)(k0 + w * 16 + l15) * 64;
  const nl75_bf8 b0 = *(const nl75_bf8*)&phB[kr + quad * 8];
  const nl75_bf8 b1 = *(const nl75_bf8*)&phB[kr + 32 + quad * 8];
  const int qtN = 32 / qsplit, qtBeg = qs * qtN;
  nl75_stage64(thB + (size_t)(qtBeg * 64) * 64, 64, thL[0], tid);
  __syncthreads();
  float M = -1e30f, S = 0.0f;
  for (int qt = qtBeg; qt < qtBeg + qtN; qt++) {
    const int cur = (qt - qtBeg) & 1;
    if (qt + 1 < qtBeg + qtN)
      nl75_stage64(thB + (size_t)((qt + 1) * 64) * 64, 64, thL[cur ^ 1], tid);
    __builtin_amdgcn_s_setprio(1);
#pragma unroll
    for (int q16 = 0; q16 < 4; q16++) {
      const int qr = q16 * 16 + l15;
      const int sw = (qr & 7) << 3;
      const nl75_bf8 a0 = *(const nl75_bf8*)&thL[cur][qr * 64 + ((quad * 8) ^ sw)];
      const nl75_bf8 a1 =
          *(const nl75_bf8*)&thL[cur][qr * 64 + ((32 + quad * 8) ^ sw)];
      nl75_f4 c = {0.0f, 0.0f, 0.0f, 0.0f};
      c = __builtin_amdgcn_mfma_f32_16x16x32_bf16(a0, b0, c, 0, 0, 0);
      c = __builtin_amdgcn_mfma_f32_16x16x32_bf16(a1, b1, c, 0, 0, 0);
      float mx = fmaxf(fmaxf(c[0], c[1]), fmaxf(c[2], c[3]));
      float nM = fmaxf(M, mx);
      float sum = __expf(c[0] - nM) + __expf(c[1] - nM) + __expf(c[2] - nM) +
                  __expf(c[3] - nM);
      S = S * __expf(M - nM) + sum;
      M = nM;
    }
    __builtin_amdgcn_s_setprio(0);
    __syncthreads();
  }
#pragma unroll
  for (int off = 16; off <= 32; off <<= 1) {
    float Mo = __shfl_xor(M, off);
    float So = __shfl_xor(S, off);
    float nM = fmaxf(M, Mo);
    S = S * __expf(M - nM) + So * __expf(Mo - nM);
    M = nM;
  }
  if (quad == 0) {
    const long long base = ((long long)(qs * nb + bl)) * NL75_TN + k0;
    Mp[base + w * 16 + l15] = M;
    Sp[base + w * 16 + l15] = S;
  }
}

// ---- combine partial stats: ek = M*log2e + log2(S); grid (nb, 8) -----------
__global__ void nl75_sred(const float* Mp, const float* Sp, float* ekW, int nb,
                          int qsplit) {
  const int bl = blockIdx.x;
  const int k = blockIdx.y * 256 + threadIdx.x;
  float M = -1e30f;
  for (int qs = 0; qs < qsplit; qs++)
    M = fmaxf(M, Mp[((size_t)(qs * nb + bl)) * NL75_TN + k]);
  float S = 0.0f;
  for (int qs = 0; qs < qsplit; qs++) {
    size_t idx = ((size_t)(qs * nb + bl)) * NL75_TN + k;
    S += Sp[idx] * __expf(Mp[idx] - M);
  }
  ekW[(size_t)bl * NL75_TN + k] = M * NL75_L2E + __log2f(S);
}

// ------------- attention apply + PV (dbuf-LDS phi/g, base-2 softmax) --------
// grid 1D (16*ksplit*nb), block 256, bl fastest (XCD pinning). LDS 32 KB.
__global__ void nl75_attn(const unsigned short* thT, const unsigned short* phT,
                          const unsigned short* gN, const float* ekW,
                          float* yPart, int nb, int ksplit) {
  __shared__ unsigned short phL[2][64 * 64];
  __shared__ unsigned short gL[2][64 * 64];
  const int wg = blockIdx.x;
  const int bl = wg % nb;
  const int rest = wg / nb;
  const int qt = rest & 15, ks = rest >> 4;
  const int tid = threadIdx.x, lane = tid & 63, w = tid >> 6;
  const int l15 = lane & 15, quad = lane >> 4;
  const int q0 = qt * 128;
  const unsigned short* thB = thT + (size_t)bl * NL75_TN * 64;
  const unsigned short* phB = phT + (size_t)bl * NL75_TN * 64;
  const unsigned short* gB = gN + (size_t)bl * NL75_MID * NL75_TN;
  const float* ekB = ekW + (size_t)bl * NL75_TN;
  const int ktN = 32 / ksplit;
  const int ktBeg = ks * ktN, ktEnd = ktBeg + ktN;
  // prologue: stage first tiles
  nl75_stage64(phB + (size_t)(ktBeg * 64) * 64, 64, phL[0], tid);
  nl75_stage64(gB + ktBeg * 64, NL75_TN, gL[0], tid);
  // theta frags for the 2 q-tiles (global, linear layout, loaded once)
  nl75_bf8 aq[2][2];
#pragma unroll
  for (int s = 0; s < 2; s++) {
    const size_t qr = (size_t)(q0 + s * 64 + w * 16 + l15) * 64;
    aq[s][0] = *(const nl75_bf8*)&thB[qr + quad * 8];
    aq[s][1] = *(const nl75_bf8*)&thB[qr + 32 + quad * 8];
  }
  nl75_f4 yacc[2][4];
#pragma unroll
  for (int s = 0; s < 2; s++)
#pragma unroll
    for (int i = 0; i < 4; i++) yacc[s][i] = (nl75_f4){0.0f, 0.0f, 0.0f, 0.0f};
  __syncthreads();
  union Frag { nl75_bf8 h; unsigned int u[4]; };
  for (int kt = ktBeg; kt < ktEnd; kt++) {
    const int cur = (kt - ktBeg) & 1;
    const int k0 = kt * 64;
    if (kt + 1 < ktEnd) {
      nl75_stage64(phB + (size_t)((kt + 1) * 64) * 64, 64, phL[cur ^ 1], tid);
      nl75_stage64(gB + (kt + 1) * 64, NL75_TN, gL[cur ^ 1], tid);
    }
    // ek prefetch for this k-tile (lane needs k = k0 + t*16 + quad*4 + r)
    nl75_f4 ek[4];
#pragma unroll
    for (int t = 0; t < 4; t++)
      ek[t] = *(const nl75_f4*)&ekB[k0 + t * 16 + quad * 4];
    __builtin_amdgcn_s_setprio(1);
    // QK swapped: lane holds C'[k = k0+t*16+4*quad+r][q = q0+s*64+w*16+l15]
    unsigned int pk[2][8];
#pragma unroll
    for (int t = 0; t < 4; t++) {
      const int krr = t * 16 + l15;
      const int sw = (krr & 7) << 3;
      const nl75_bf8 b0 =
          *(const nl75_bf8*)&phL[cur][krr * 64 + ((quad * 8) ^ sw)];
      const nl75_bf8 b1 =
          *(const nl75_bf8*)&phL[cur][krr * 64 + ((32 + quad * 8) ^ sw)];
#pragma unroll
      for (int s = 0; s < 2; s++) {
        nl75_f4 c = {0.0f, 0.0f, 0.0f, 0.0f};
        c = __builtin_amdgcn_mfma_f32_16x16x32_bf16(b0, aq[s][0], c, 0, 0, 0);
        c = __builtin_amdgcn_mfma_f32_16x16x32_bf16(b1, aq[s][1], c, 0, 0, 0);
        // P = exp(c - M)/S = exp2(c*log2e - ek)
        pk[s][t * 2 + 0] =
            nl75_pkbf16(nl75_exp2(fmaf(c[0], NL75_L2E, -ek[t][0])),
                        nl75_exp2(fmaf(c[1], NL75_L2E, -ek[t][1])));
        pk[s][t * 2 + 1] =
            nl75_pkbf16(nl75_exp2(fmaf(c[2], NL75_L2E, -ek[t][2])),
                        nl75_exp2(fmaf(c[3], NL75_L2E, -ek[t][3])));
      }
    }
    // PV: A-frag = own pk regs; B-frag = g rows with matching slot relabel:
    // slot 8q+j -> k = 16*(j>>2) + 4*q + (j&3).
#pragma unroll
    for (int mtile = 0; mtile < 4; mtile++) {
      const int m = mtile * 16 + l15;
      const int sw = (m & 7) << 3;
      const unsigned short* row = &gL[cur][m * 64];
      Frag bg0, bg1;
      *(uint2*)&bg0.u[0] = *(const uint2*)&row[(quad * 4) ^ sw];
      *(uint2*)&bg0.u[2] = *(const uint2*)&row[(16 + quad * 4) ^ sw];
      *(uint2*)&bg1.u[0] = *(const uint2*)&row[(32 + quad * 4) ^ sw];
      *(uint2*)&bg1.u[2] = *(const uint2*)&row[(48 + quad * 4) ^ sw];
#pragma unroll
      for (int s = 0; s < 2; s++) {
        Frag a0, a1;
        a0.u[0] = pk[s][0]; a0.u[1] = pk[s][1];
        a0.u[2] = pk[s][2]; a0.u[3] = pk[s][3];
        a1.u[0] = pk[s][4]; a1.u[1] = pk[s][5];
        a1.u[2] = pk[s][6]; a1.u[3] = pk[s][7];
        yacc[s][mtile] = __builtin_amdgcn_mfma_f32_16x16x32_bf16(
            a0.h, bg0.h, yacc[s][mtile], 0, 0, 0);
        yacc[s][mtile] = __builtin_amdgcn_mfma_f32_16x16x32_bf16(
            a1.h, bg1.h, yacc[s][mtile], 0, 0, 0);
      }
    }
    __builtin_amdgcn_s_setprio(0);
    __syncthreads();
  }
  // direct float4 y-store: lane holds y[m][q0 + s*64 + w*16 + quad*4 + r]
  float* yB = yPart + ((size_t)(ks * nb + bl) * NL75_MID) * NL75_TN;
#pragma unroll
  for (int s = 0; s < 2; s++)
#pragma unroll
    for (int mtile = 0; mtile < 4; mtile++) {
      float4 v = make_float4(yacc[s][mtile][0], yacc[s][mtile][1],
                             yacc[s][mtile][2], yacc[s][mtile][3]);
      *(float4*)&yB[(size_t)(mtile * 16 + l15) * NL75_TN + q0 + s * 64 +
                    w * 16 + quad * 4] = v;
    }
}

// ------- streaming ksplit-reduction: y = sum_ks yPart[ks] -------------------
__global__ void nl75_yred(const float* yPart, float* y, int nb, int ksplit) {
  const size_t tot = (size_t)nb * NL75_MID * NL75_TN / 4;
  const size_t stride = tot;
  const float4* src = (const float4*)yPart;
  float4* dst = (float4*)y;
  for (size_t i = (size_t)blockIdx.x * 256 + threadIdx.x; i < tot;
       i += (size_t)gridDim.x * 256) {
    float4 a = src[i];
    for (int ks = 1; ks < ksplit; ks++) {
      float4 b = src[(size_t)ks * stride + i];
      a.x += b.x; a.y += b.y; a.z += b.z; a.w += b.w;
    }
    dst[i] = a;
  }
}

// ------- fused refine GEMM + scatter + residual (coalesced epilogue) --------
// grid (nb, 16, 4), block 256.
__global__ void nl75_refsc(const float* yIn, const float* rW, const float* rB,
                           const float* pc, float* outP, int bOff, int nb,
                           int ksplit) {
  __shared__ float rwS[32][66];
  __shared__ float yS[NL75_MID][132];  // reused as outS[8][516] after GEMM
  const int bl = blockIdx.x, cg = blockIdx.y, t = blockIdx.z;
  const int b = bOff + bl, c0 = cg * 8, tid = threadIdx.x;
  for (int i = tid; i < 32 * NL75_MID; i += 256) {
    int oh = i >> 6, m = i & 63;
    rwS[oh][m] = rW[(long long)(t * 32 + oh) * NL75_MID + m];
  }
  if (ksplit == 1) {
    const float* yB0 = yIn + (size_t)bl * NL75_MID * NL75_TN;
    for (int i = tid; i < NL75_MID * 32; i += 256) {
      int m = i >> 5, r = i & 31;       // r = i16*2 + half
      int i16 = r >> 1, half = r & 1;
      const float4 v = *(const float4*)&yB0[(size_t)m * NL75_TN + i16 * 128 +
                                            c0 + half * 4];
      *(float4*)&yS[m][i16 * 8 + half * 4] = v;
    }
  } else {
    for (int i = tid; i < NL75_MID * 128; i += 256) {
      int m = i >> 7, qi = i & 127;
      int i16 = qi >> 3, cl = qi & 7;
      long long off = (long long)m * NL75_TN + i16 * 128 + c0 + cl;
      float v = 0.0f;
      for (int ks = 0; ks < ksplit; ks++)
        v += yIn[((long long)(ks * nb + bl) * NL75_MID) * NL75_TN + off];
      yS[m][qi] = v;
    }
  }
  __syncthreads();
  const int oh0 = (tid >> 5) * 4;
  const int q4 = (tid & 31) * 4;
  float acc[4][4];
#pragma unroll
  for (int i = 0; i < 4; i++) {
    float bias = rB[t * 32 + oh0 + i];
#pragma unroll
    for (int j = 0; j < 4; j++) acc[i][j] = bias;
  }
  for (int m = 0; m < NL75_MID; m++) {
    float yv[4];
#pragma unroll
    for (int j = 0; j < 4; j++) yv[j] = yS[m][q4 + j];
#pragma unroll
    for (int i = 0; i < 4; i++) {
      float w = rwS[oh0 + i][m];
#pragma unroll
      for (int j = 0; j < 4; j++) acc[i][j] = fmaf(w, yv[j], acc[i][j]);
    }
  }
  __syncthreads();  // all yS reads done before outS overwrite
  float* outS = &yS[0][0];
  const int NP = 516;
#pragma unroll
  for (int i = 0; i < 4; i++) {
    const int oh = oh0 + i;
#pragma unroll
    for (int j = 0; j < 4; j++) {
      const int qi = q4 + j;
      outS[(qi & 7) * NP + oh * 16 + (qi >> 3)] = fmaxf(acc[i][j], 0.0f);
    }
  }
  __syncthreads();
  const size_t obase = (((size_t)b * 128 + c0) * 4 + t) * 512;
#pragma unroll
  for (int ii = 0; ii < 4; ii++) {
    const int fi = ii * 256 + tid;
    const int cl = fi >> 7, n0 = (fi & 127) * 4;
    float4 v = *(const float4*)&outS[cl * NP + n0];
    const size_t gi = obase + (size_t)cl * 4 * 512 + n0;
    const float4 p = *(const float4*)&pc[gi];
    v.x += p.x; v.y += p.y; v.z += p.z; v.w += p.w;
    *(float4*)&outP[gi] = v;
  }
}

extern "C" void kernel_launch(void* const* d_in, const int* in_sizes, int n_in,
                              void* d_out, int out_size, void* d_ws, size_t ws_size,
                              hipStream_t stream) {
  const float* pc = (const float*)d_in[0];
  const float* tw = (const float*)d_in[1];
  const float* tb = (const float*)d_in[2];
  const float* pw = (const float*)d_in[3];
  const float* pb = (const float*)d_in[4];
  const float* gw = (const float*)d_in[5];
  const float* gb = (const float*)d_in[6];
  const float* rw = (const float*)d_in[7];
  const float* rb = (const float*)d_in[8];
  float* out = (float*)d_out;

  const size_t yPB = (size_t)NL75_MID * NL75_TN;             // floats
  const size_t bfB8 = 3ull * 8 * NL75_TN * 64 * 2;           // bf16 proj, nb=8
  const size_t base8 = bfB8 + 2ull * 8 * NL75_TN * 4;        // + s1/ekW
  auto need = [&](int qs, int ks, int yr) -> size_t {
    return base8 + (2ull * qs * 8 * NL75_TN + (size_t)ks * 8 * yPB +
                    (size_t)yr * 8 * yPB) * 4;
  };
  const size_t needMid = base8 + 8ull * yPB * 4;

  int nb, qsplit, ksplit;
  bool alias, yred;
  if (ws_size >= need(8, 8, 1)) {
    nb = 8; qsplit = 8; ksplit = 8; alias = false; yred = true;
  } else if (ws_size >= need(8, 4, 1)) {
    nb = 8; qsplit = 8; ksplit = 4; alias = false; yred = true;
  } else if (ws_size >= need(4, 4, 1)) {
    nb = 8; qsplit = 4; ksplit = 4; alias = false; yred = true;
  } else if (ws_size >= need(4, 4, 0)) {
    nb = 8; qsplit = 4; ksplit = 4; alias = false; yred = false;
  } else if (ws_size >= needMid) {
    nb = 8; qsplit = 1; ksplit = 1; alias = true; yred = false;
  } else {
    nb = 1; qsplit = 1; ksplit = 1; alias = true; yred = false;
  }
  const int nloop = 8 / nb;

  unsigned short* thT = (unsigned short*)d_ws;
  unsigned short* phT = thT + (size_t)nb * NL75_TN * 64;
  unsigned short* gN = phT + (size_t)nb * NL75_TN * 64;
  float* s1 = (float*)(gN + (size_t)nb * NL75_MID * NL75_TN);  // nb*TN
  float* ekW = s1 + (size_t)nb * NL75_TN;                      // nb*TN
  float *Mp, *Sp, *yPart, *yFull;
  if (alias) {
    Mp = s1; Sp = ekW;  // sred writes ekW in-place after reading Sp (qs=1)
    yPart = ekW + (size_t)nb * NL75_TN;
    yFull = yPart;
  } else {
    Mp = ekW + (size_t)nb * NL75_TN;
    Sp = Mp + (size_t)qsplit * nb * NL75_TN;
    yPart = Sp + (size_t)qsplit * nb * NL75_TN;
    yFull = yPart + (size_t)ksplit * nb * yPB;
  }

  for (int l = 0; l < nloop; l++) {
    const int bOff = l * nb;
    nl75_proj<<<dim3(nb, 3, 32), 256, 0, stream>>>(pc, tw, tb, pw, pb, gw, gb,
                                                   thT, phT, gN, bOff, nb);
    nl75_stats<<<dim3(nb, 32 * qsplit), 256, 0, stream>>>(thT, phT, Mp, Sp,
                                                          nb, qsplit);
    nl75_sred<<<dim3(nb, 8), 256, 0, stream>>>(Mp, Sp, ekW, nb, qsplit);
    nl75_attn<<<dim3(16 * ksplit * nb), 256, 0, stream>>>(thT, phT, gN, ekW,
                                                          yPart, nb, ksplit);
    if (yred) {
      nl75_yred<<<dim3(1024), 256, 0, stream>>>(yPart, yFull, nb, ksplit);
      nl75_refsc<<<dim3(nb, 16, 4), 256, 0, stream>>>(yFull, rw, rb, pc, out,
                                                      bOff, nb, 1);
    } else {
      nl75_refsc<<<dim3(nb, 16, 4), 256, 0, stream>>>(yPart, rw, rb, pc, out,
                                                      bOff, nb, ksplit);
    }
  }
}